// Round 3
// baseline (3609.752 us; speedup 1.0000x reference)
//
#include <hip/hip_runtime.h>
#include <hip/hip_bf16.h>

typedef __hip_bfloat16 bf16;

#define NB 4
#define NCH 64
#define HW 2304      // 48*48
#define NP 7470      // total patches across 5 scales
#define SW 7472      // padded scores row stride (16B-aligned rows)

__device__ __forceinline__ float b2f(bf16 v){ return __bfloat162float(v); }
__device__ __forceinline__ float us2f(unsigned short u){
  unsigned v = (unsigned)u << 16; float f; __builtin_memcpy(&f, &v, 4); return f;
}

// n -> (scale offset, dim, y, x). dims: 48,43,38,33,28 ; offsets 0,2304,4153,5597,6686
__device__ __forceinline__ void n_decode(int n, int& off, int& d, int& y, int& x){
  if (n < 2304)      { off = 0;    d = 48; }
  else if (n < 4153) { off = 2304; d = 43; }
  else if (n < 5597) { off = 4153; d = 38; }
  else if (n < 6686) { off = 5597; d = 33; }
  else               { off = 6686; d = 28; }
  int l = n - off; y = l / d; x = l - y * d;
}

// ---- dtype probe: is input memory bf16 (1) or fp32 (0)? ----
__global__ __launch_bounds__(256) void k_detect(const void* __restrict__ x, int* __restrict__ flag){
  const unsigned short* u = (const unsigned short*)x;
  int tid = threadIdx.x;
  int c = 0;
  for (int i = tid; i < 8192; i += 256){
    float v = us2f(u[i]);
    float a = fabsf(v);
    if (v == 0.f || (a > 1e-5f && a < 1e3f)) c++;   // NaN/inf fail both
  }
  #pragma unroll
  for (int o = 1; o < 64; o <<= 1) c += __shfl_xor(c, o);
  __shared__ int wr[4];
  if ((tid & 63) == 0) wr[tid >> 6] = c;
  __syncthreads();
  if (tid == 0) flag[0] = ((wr[0]+wr[1]+wr[2]+wr[3]) > 7000) ? 1 : 0;
}

// canonical fp32 copy of an input
__global__ __launch_bounds__(256) void k_canon(const void* __restrict__ src, float* __restrict__ dst,
                                               int n, const int* __restrict__ flag){
  int id = blockIdx.x * 256 + threadIdx.x;
  if (id >= n) return;
  if (flag[0]) dst[id] = us2f(((const unsigned short*)src)[id]);
  else         dst[id] = ((const float*)src)[id];
}

// Bilinear resize (JAX half-pixel, antialias=False) of xc into xs[b][c][n], fp32.
__global__ __launch_bounds__(256) void k_resize(const float* __restrict__ x, float* __restrict__ xs){
  int id = blockIdx.x * 256 + threadIdx.x;
  if (id >= NB * NP) return;
  int b = id / NP, n = id - b * NP;
  int off, d, y, xx; n_decode(n, off, d, y, xx);
  const float* xb = x + (size_t)b * NCH * HW;
  float* o = xs + (size_t)b * NCH * NP + n;
  if (off == 0){
    int p = y * 48 + xx;
    for (int c = 0; c < NCH; c++) o[(size_t)c * NP] = xb[c * HW + p];
  } else {
    float cy = (y + 0.5f) * (48.0f / (float)d) - 0.5f;
    float cx = (xx + 0.5f) * (48.0f / (float)d) - 0.5f;
    int y0 = (int)floorf(cy), x0 = (int)floorf(cx);
    float fy = cy - (float)y0, fx = cx - (float)x0;
    int y1 = min(y0 + 1, 47), x1 = min(x0 + 1, 47);
    y0 = max(y0, 0); x0 = max(x0, 0);
    float w00 = (1.f-fy)*(1.f-fx), w01 = (1.f-fy)*fx, w10 = fy*(1.f-fx), w11 = fy*fx;
    for (int c = 0; c < NCH; c++){
      const float* pc = xb + c * HW;
      float v = w00 * pc[y0*48+x0] + w01 * pc[y0*48+x1]
              + w10 * pc[y1*48+x0] + w11 * pc[y1*48+x1];
      o[(size_t)c * NP] = v;
    }
  }
}

// 1x1 conv (Cin=64) + PReLU; in fp32 [64][rs_in] per batch; out fp32 or bf16.
template<bool OB>
__global__ __launch_bounds__(256) void k_conv1x1(const float* __restrict__ in, const float* __restrict__ Wt,
    const float* __restrict__ bias, const float* __restrict__ alpha, void* __restrict__ outv,
    int npix, int cout, size_t in_bstride, size_t out_bstride, int rs_in, int rs_out){
  __shared__ float Wl[64*64];
  __shared__ float it[64][64];
  int b = blockIdx.y;
  int n0 = blockIdx.x * 64;
  int tid = threadIdx.x;
  const float* ib = in + (size_t)b * in_bstride;
  for (int i = tid; i < cout * 64; i += 256) Wl[i] = Wt[i];
  for (int i = tid; i < 64 * 64; i += 256){
    int ci = i >> 6, nn = i & 63;
    int n = n0 + nn;
    it[ci][nn] = (n < npix) ? ib[(size_t)ci * rs_in + n] : 0.f;
  }
  __syncthreads();
  float al = alpha[0];
  for (int oi = tid; oi < cout * 64; oi += 256){
    int co = oi >> 6, nn = oi & 63;
    float acc = bias[co];
    #pragma unroll
    for (int ci = 0; ci < 64; ci++) acc = fmaf(Wl[co*64+ci], it[ci][nn], acc);
    acc = acc >= 0.f ? acc : al * acc;
    int n = n0 + nn;
    if (n < npix){
      size_t idx = (size_t)b * out_bstride + (size_t)co * rs_out + n;
      if constexpr (OB) ((bf16*)outv)[idx] = __float2bfloat16(acc);
      else              ((float*)outv)[idx] = acc;
    }
  }
}

// 1/max(||mat patch||,1e-4) per (b,n); mat fp32 [b][32][NP]
__global__ __launch_bounds__(256) void k_norminv(const float* __restrict__ mat, float* __restrict__ ninv){
  int id = blockIdx.x * 256 + threadIdx.x;
  if (id >= NB * NP) return;
  int b = id / NP, n = id - b * NP;
  int off, d, y, x; n_decode(n, off, d, y, x);
  const float* mp = mat + (size_t)b * 32 * NP + off;
  float s = 0.f;
  for (int c = 0; c < 32; c++){
    const float* pc = mp + (size_t)c * NP;
    #pragma unroll
    for (int dy = -1; dy <= 1; dy++){
      int yy = y + dy; if (yy < 0 || yy >= d) continue;
      #pragma unroll
      for (int dx = -1; dx <= 1; dx++){
        int xx = x + dx; if (xx < 0 || xx >= d) continue;
        float v = pc[yy * d + xx]; s += v * v;
      }
    }
  }
  ninv[id] = 1.f / fmaxf(sqrtf(s), 1e-4f);
}

// unfold match_base (batch b) -> U[2304][288] fp32, zero-padded borders
__global__ __launch_bounds__(256) void k_packU(const float* __restrict__ mb, float* __restrict__ U, int b){
  int id = blockIdx.x * 256 + threadIdx.x;
  if (id >= HW * 288) return;
  int p = id / 288, k = id - p * 288;
  int c = k / 9, r = k - c * 9, kh = r / 3, kw = r - kh * 3;
  int y = p / 48 + kh - 1, x = (p % 48) + kw - 1;
  float v = 0.f;
  if (y >= 0 && y < 48 && x >= 0 && x < 48)
    v = mb[((size_t)b * 32 + c) * HW + y * 48 + x];
  U[id] = v;
}

// unfold mat (fp32) -> Wp[NP][288] fp32
__global__ __launch_bounds__(256) void k_packF(const float* __restrict__ src, float* __restrict__ dst, int b){
  int id = blockIdx.x * 256 + threadIdx.x;
  if (id >= NP * 288) return;
  int n = id / 288, k = id - n * 288;
  int c = k / 9, r = k - c * 9, kh = r / 3, kw = r - kh * 3;
  int off, d, y, x; n_decode(n, off, d, y, x);
  int yy = y + kh - 1, xx = x + kw - 1;
  float v = 0.f;
  if (yy >= 0 && yy < d && xx >= 0 && xx < d)
    v = src[((size_t)b * 32 + c) * NP + off + yy * d + xx];
  dst[id] = v;
}

// unfold base (bf16) -> Rp[NP][576] bf16
__global__ __launch_bounds__(256) void k_packH(const bf16* __restrict__ src, bf16* __restrict__ dst, int b){
  int id = blockIdx.x * 256 + threadIdx.x;
  if (id >= NP * 576) return;
  int n = id / 576, k = id - n * 576;
  int c = k / 9, r = k - c * 9, kh = r / 3, kw = r - kh * 3;
  int off, d, y, x; n_decode(n, off, d, y, x);
  int yy = y + kh - 1, xx = x + kw - 1;
  bf16 v = __float2bfloat16(0.f);
  if (yy >= 0 && yy < d && xx >= 0 && xx < d)
    v = src[((size_t)b * 64 + c) * NP + off + yy * d + xx];
  dst[id] = v;
}

// S[mloc][n] = 10*ninv[n]*dot(U[r0+mloc,:288], Wp[n,:288])
__global__ __launch_bounds__(256) void k_gemm1(const float* __restrict__ A, const float* __restrict__ Bm,
    const float* __restrict__ ninv, float* __restrict__ S, int r0){
  __shared__ float As[16][68];
  __shared__ float Bs[16][68];
  int m0 = blockIdx.y * 64, n0 = blockIdx.x * 64;
  int tid = threadIdx.x, tx = tid & 15, ty = tid >> 4;
  int lr = tid >> 2, lk = (tid & 3) * 4;
  float acc[4][4] = {};
  for (int k0 = 0; k0 < 288; k0 += 16){
    float4 av = *reinterpret_cast<const float4*>(A + (size_t)(r0 + m0 + lr) * 288 + k0 + lk);
    As[lk+0][lr] = av.x; As[lk+1][lr] = av.y; As[lk+2][lr] = av.z; As[lk+3][lr] = av.w;
    int nr = n0 + lr;
    float4 bv = make_float4(0.f, 0.f, 0.f, 0.f);
    if (nr < NP) bv = *reinterpret_cast<const float4*>(Bm + (size_t)nr * 288 + k0 + lk);
    Bs[lk+0][lr] = bv.x; Bs[lk+1][lr] = bv.y; Bs[lk+2][lr] = bv.z; Bs[lk+3][lr] = bv.w;
    __syncthreads();
    #pragma unroll
    for (int kk = 0; kk < 16; kk++){
      float4 af = *reinterpret_cast<const float4*>(&As[kk][ty*4]);
      float a4[4] = {af.x, af.y, af.z, af.w};
      float b4[4] = {Bs[kk][tx], Bs[kk][tx+16], Bs[kk][tx+32], Bs[kk][tx+48]};
      #pragma unroll
      for (int i = 0; i < 4; i++)
        #pragma unroll
        for (int j = 0; j < 4; j++)
          acc[i][j] = fmaf(a4[i], b4[j], acc[i][j]);
    }
    __syncthreads();
  }
  #pragma unroll
  for (int i = 0; i < 4; i++){
    int m = m0 + ty*4 + i;
    #pragma unroll
    for (int j = 0; j < 4; j++){
      int n = n0 + tx + 16*j;
      if (n < NP) S[(size_t)m * SW + n] = acc[i][j] * 10.f * ninv[n];
    }
  }
}

__device__ __forceinline__ float wredmax(float v){
  #pragma unroll
  for (int o = 1; o < 64; o <<= 1) v = fmaxf(v, __shfl_xor(v, o));
  return v;
}
__device__ __forceinline__ float wredsum(float v){
  #pragma unroll
  for (int o = 1; o < 64; o <<= 1) v += __shfl_xor(v, o);
  return v;
}

// row softmax over n<NP: writes exp(s-max) in place, rsi[p]=1/sum
__global__ __launch_bounds__(256) void k_softmax(float* __restrict__ S, float* __restrict__ rsi){
  int p = blockIdx.x;
  float* row = S + (size_t)p * SW;
  int tid = threadIdx.x;
  __shared__ float wrm[4], wrs[4];
  float m = -3.0e38f;
  for (int i = tid; i < NP; i += 256) m = fmaxf(m, row[i]);
  m = wredmax(m);
  if ((tid & 63) == 0) wrm[tid >> 6] = m;
  __syncthreads();
  m = fmaxf(fmaxf(wrm[0], wrm[1]), fmaxf(wrm[2], wrm[3]));
  float s = 0.f;
  for (int i = tid; i < NP; i += 256){
    float e = __expf(row[i] - m);
    row[i] = e;
    s += e;
  }
  s = wredsum(s);
  if ((tid & 63) == 0) wrs[tid >> 6] = s;
  __syncthreads();
  if (tid == 0) rsi[p] = 1.f / (wrs[0] + wrs[1] + wrs[2] + wrs[3]);
}

// T[r0+mloc][j] = rsi[mloc] * sum_k S[mloc][k] * Rp[k][j], K=NP, N=576; Rp bf16
__global__ __launch_bounds__(256) void k_gemm2(const float* __restrict__ A, const bf16* __restrict__ Bm,
    const float* __restrict__ rsi, float* __restrict__ T, int r0){
  __shared__ float As[16][68];
  __shared__ float Bs[16][68];
  int m0 = blockIdx.y * 64, n0 = blockIdx.x * 64;
  int tid = threadIdx.x, tx = tid & 15, ty = tid >> 4;
  int lr = tid >> 2, lk = (tid & 3) * 4;
  float acc[4][4] = {};
  for (int k0 = 0; k0 < NP; k0 += 16){
    const float* ap = A + (size_t)(m0 + lr) * SW + k0 + lk;
    if (k0 + 16 <= NP){
      float4 av = *reinterpret_cast<const float4*>(ap);
      As[lk+0][lr] = av.x; As[lk+1][lr] = av.y; As[lk+2][lr] = av.z; As[lk+3][lr] = av.w;
    } else {
      #pragma unroll
      for (int j = 0; j < 4; j++) As[lk+j][lr] = (k0 + lk + j < NP) ? ap[j] : 0.f;
    }
    {
      int kk = tid >> 4, nn4 = (tid & 15) * 4;
      float v0 = 0.f, v1 = 0.f, v2 = 0.f, v3 = 0.f;
      if (k0 + kk < NP){
        ushort4 u = *reinterpret_cast<const ushort4*>(
            reinterpret_cast<const unsigned short*>(Bm) + (size_t)(k0+kk)*576 + n0 + nn4);
        v0 = us2f(u.x); v1 = us2f(u.y); v2 = us2f(u.z); v3 = us2f(u.w);
      }
      Bs[kk][nn4+0] = v0; Bs[kk][nn4+1] = v1; Bs[kk][nn4+2] = v2; Bs[kk][nn4+3] = v3;
    }
    __syncthreads();
    #pragma unroll
    for (int kk = 0; kk < 16; kk++){
      float4 af = *reinterpret_cast<const float4*>(&As[kk][ty*4]);
      float a4[4] = {af.x, af.y, af.z, af.w};
      float b4[4] = {Bs[kk][tx], Bs[kk][tx+16], Bs[kk][tx+32], Bs[kk][tx+48]};
      #pragma unroll
      for (int i = 0; i < 4; i++)
        #pragma unroll
        for (int j = 0; j < 4; j++)
          acc[i][j] = fmaf(a4[i], b4[j], acc[i][j]);
    }
    __syncthreads();
  }
  #pragma unroll
  for (int i = 0; i < 4; i++){
    int m = m0 + ty*4 + i;
    float r = rsi[m];
    #pragma unroll
    for (int j = 0; j < 4; j++)
      T[(size_t)(r0 + m) * 576 + n0 + tx + 16*j] = acc[i][j] * r;
  }
}

// out[b,co,y,x] = x + 0.25 * fold(T); output dtype per flag (0=f32, 1=bf16)
__global__ __launch_bounds__(256) void k_fold(const float* __restrict__ T, const float* __restrict__ x,
    void* __restrict__ out, int b, const int* __restrict__ flag){
  int id = blockIdx.x * 256 + threadIdx.x;
  if (id >= 64 * HW) return;
  int co = id / HW, p = id - co * HW;
  int y = p / 48, xx = p - y * 48;
  float acc = 0.f;
  #pragma unroll
  for (int dy = -1; dy <= 1; dy++){
    int yy = y + dy; if (yy < 0 || yy >= 48) continue;
    #pragma unroll
    for (int dx = -1; dx <= 1; dx++){
      int x2 = xx + dx; if (x2 < 0 || x2 >= 48) continue;
      acc += T[(size_t)(yy*48 + x2) * 576 + co*9 + (1-dy)*3 + (1-dx)];
    }
  }
  size_t gi = (size_t)b * 64 * HW + id;
  float r = x[gi] + 0.25f * acc;
  if (flag[0]) ((bf16*)out)[gi] = __float2bfloat16(r);
  else         ((float*)out)[gi] = r;
}

extern "C" void kernel_launch(void* const* d_in, const int* in_sizes, int n_in,
                              void* d_out, int out_size, void* d_ws, size_t ws_size,
                              hipStream_t stream){
  (void)out_size;

  char* cur = (char*)d_ws;
  auto carve = [&](size_t bytes)->char*{
    char* p = cur; cur += (bytes + 255) & ~(size_t)255; return p;
  };
  int*   flag  = (int*)  carve(4);
  // canonical fp32 inputs
  float* canon[10];
  for (int i = 0; i < 10; i++) canon[i] = (float*)carve((size_t)in_sizes[i] * 4);
  float* xc = canon[0];
  float* Wb = canon[1]; float* bb = canon[2]; float* ab = canon[3];
  float* Wm = canon[4]; float* bm = canon[5]; float* am = canon[6];
  float* Wa = canon[7]; float* ba = canon[8]; float* aa = canon[9];

  float* xs    = (float*)carve((size_t)NB * 64 * NP * 4);   // resized x fp32
  float* mbuf  = (float*)carve((size_t)NB * 32 * HW * 4);   // match_base fp32
  float* mat   = (float*)carve((size_t)NB * 32 * NP * 4);   // conv_match fp32
  float* ninv  = (float*)carve((size_t)NB * NP * 4);
  bf16*  baseh = (bf16*) carve((size_t)NB * 64 * NP * 2);   // conv_assembly bf16
  float* U     = (float*)carve((size_t)HW * 288 * 4);       // per-batch
  float* Wp    = (float*)carve((size_t)NP * 288 * 4);       // per-batch
  bf16*  Rp    = (bf16*) carve((size_t)NP * 576 * 2);       // per-batch
  float* T     = (float*)carve((size_t)HW * 576 * 4);       // per-batch
  float* rsi   = (float*)carve((size_t)HW * 4);

  size_t used = (size_t)(cur - (char*)d_ws);
  size_t avail = (ws_size > used) ? (ws_size - used) : 0;
  int chunkM = 64;
  const int opts[6] = {2304, 1152, 576, 384, 192, 64};
  for (int i = 0; i < 6; i++){
    if ((size_t)opts[i] * SW * 4 <= avail){ chunkM = opts[i]; break; }
  }
  float* S = (float*)cur;  // [chunkM][SW]

  k_detect<<<1, 256, 0, stream>>>(d_in[0], flag);
  for (int i = 0; i < 10; i++)
    k_canon<<<(in_sizes[i] + 255)/256, 256, 0, stream>>>(d_in[i], canon[i], in_sizes[i], flag);

  k_resize<<<(NB*NP + 255)/256, 256, 0, stream>>>(xc, xs);

  dim3 gm((NP + 63)/64, NB);
  k_conv1x1<false><<<gm, 256, 0, stream>>>(xs, Wm, bm, am, (void*)mat,   NP, 32, (size_t)64*NP, (size_t)32*NP, NP, NP);
  k_conv1x1<true ><<<gm, 256, 0, stream>>>(xs, Wa, ba, aa, (void*)baseh, NP, 64, (size_t)64*NP, (size_t)64*NP, NP, NP);
  dim3 gb((HW + 63)/64, NB);
  k_conv1x1<false><<<gb, 256, 0, stream>>>(xs, Wb, bb, ab, (void*)mbuf,  HW, 32, (size_t)64*NP, (size_t)32*HW, NP, HW);

  k_norminv<<<(NB*NP + 255)/256, 256, 0, stream>>>(mat, ninv);

  for (int b = 0; b < NB; b++){
    k_packU<<<(HW*288 + 255)/256, 256, 0, stream>>>(mbuf, U, b);
    k_packF<<<(NP*288 + 255)/256, 256, 0, stream>>>(mat,  Wp, b);
    k_packH<<<(NP*576 + 255)/256, 256, 0, stream>>>(baseh, Rp, b);

    for (int r0 = 0; r0 < HW; r0 += chunkM){
      dim3 g1((NP + 63)/64, chunkM/64);
      k_gemm1<<<g1, 256, 0, stream>>>(U, Wp, ninv + (size_t)b*NP, S, r0);
      k_softmax<<<chunkM, 256, 0, stream>>>(S, rsi);
      dim3 g2(576/64, chunkM/64);
      k_gemm2<<<g2, 256, 0, stream>>>(S, Rp, rsi, T, r0);
    }

    k_fold<<<(64*HW + 255)/256, 256, 0, stream>>>(T, xc, d_out, b, flag);
  }
}

// Round 4
// 659.511 us; speedup vs baseline: 5.4734x; 5.4734x over previous
//
#include <hip/hip_runtime.h>
#include <hip/hip_bf16.h>
#include <hip/hip_fp16.h>

typedef __hip_bfloat16 bf16;
typedef __attribute__((ext_vector_type(8))) short short8;
typedef __attribute__((ext_vector_type(4))) float f32x4;
typedef _Float16 f16x8 __attribute__((ext_vector_type(8)));

#define NB 4
#define NCH 64
#define HW 2304      // 48*48
#define NP 7470      // total patches across 5 scales
#define NPAD 7552    // 59*128, also 236*32
#define NT 236       // NPAD/32 k-tiles
#define SW2 NPAD     // S row stride (fp16 elems)

__device__ __forceinline__ float b2f(bf16 v){ return __bfloat162float(v); }
__device__ __forceinline__ float us2f(unsigned short u){
  unsigned v = (unsigned)u << 16; float f; __builtin_memcpy(&f, &v, 4); return f;
}
__device__ __forceinline__ short f2bs(float f){
  bf16 h = __float2bfloat16(f); short s; __builtin_memcpy(&s, &h, 2); return s;
}
__device__ __forceinline__ void gl16(const void* g, void* l){
  __builtin_amdgcn_global_load_lds((const __attribute__((address_space(1))) unsigned int*)g,
                                   (__attribute__((address_space(3))) unsigned int*)l, 16, 0, 0);
}

// n -> (scale offset, dim, y, x). dims: 48,43,38,33,28 ; offsets 0,2304,4153,5597,6686
__device__ __forceinline__ void n_decode(int n, int& off, int& d, int& y, int& x){
  if (n < 2304)      { off = 0;    d = 48; }
  else if (n < 4153) { off = 2304; d = 43; }
  else if (n < 5597) { off = 4153; d = 38; }
  else if (n < 6686) { off = 5597; d = 33; }
  else               { off = 6686; d = 28; }
  int l = n - off; y = l / d; x = l - y * d;
}

// ---- dtype probe (kept from R3: proven) ----
__global__ __launch_bounds__(256) void k_detect(const void* __restrict__ x, int* __restrict__ flag){
  const unsigned short* u = (const unsigned short*)x;
  int tid = threadIdx.x;
  int c = 0;
  for (int i = tid; i < 8192; i += 256){
    float v = us2f(u[i]);
    float a = fabsf(v);
    if (v == 0.f || (a > 1e-5f && a < 1e3f)) c++;
  }
  #pragma unroll
  for (int o = 1; o < 64; o <<= 1) c += __shfl_xor(c, o);
  __shared__ int wr[4];
  if ((tid & 63) == 0) wr[tid >> 6] = c;
  __syncthreads();
  if (tid == 0) flag[0] = ((wr[0]+wr[1]+wr[2]+wr[3]) > 7000) ? 1 : 0;
}

__global__ __launch_bounds__(256) void k_canon(const void* __restrict__ src, float* __restrict__ dst,
                                               int n, const int* __restrict__ flag){
  int id = blockIdx.x * 256 + threadIdx.x;
  if (id >= n) return;
  if (flag[0]) dst[id] = us2f(((const unsigned short*)src)[id]);
  else         dst[id] = ((const float*)src)[id];
}

// Bilinear resize (half-pixel, antialias=False): x fp32 -> xs bf16 [b][c][n]
__global__ __launch_bounds__(256) void k_resize(const float* __restrict__ x, bf16* __restrict__ xs){
  int id = blockIdx.x * 256 + threadIdx.x;
  if (id >= NB * NP) return;
  int b = id / NP, n = id - b * NP;
  int off, d, y, xx; n_decode(n, off, d, y, xx);
  const float* xb = x + (size_t)b * NCH * HW;
  bf16* o = xs + (size_t)b * NCH * NP + n;
  if (off == 0){
    int p = y * 48 + xx;
    for (int c = 0; c < NCH; c++) o[(size_t)c * NP] = __float2bfloat16(xb[c * HW + p]);
  } else {
    float cy = (y + 0.5f) * (48.0f / (float)d) - 0.5f;
    float cx = (xx + 0.5f) * (48.0f / (float)d) - 0.5f;
    int y0 = (int)floorf(cy), x0 = (int)floorf(cx);
    float fy = cy - (float)y0, fx = cx - (float)x0;
    int y1 = min(y0 + 1, 47), x1 = min(x0 + 1, 47);
    y0 = max(y0, 0); x0 = max(x0, 0);
    float w00 = (1.f-fy)*(1.f-fx), w01 = (1.f-fy)*fx, w10 = fy*(1.f-fx), w11 = fy*fx;
    for (int c = 0; c < NCH; c++){
      const float* pc = xb + c * HW;
      float v = w00 * pc[y0*48+x0] + w01 * pc[y0*48+x1]
              + w10 * pc[y1*48+x0] + w11 * pc[y1*48+x1];
      o[(size_t)c * NP] = __float2bfloat16(v);
    }
  }
}

// 1x1 conv (Cin=64) + PReLU; in bf16 [64][rs_in] per batch; out fp32 or bf16.
template<bool OB>
__global__ __launch_bounds__(256) void k_conv1x1(const bf16* __restrict__ in, const float* __restrict__ Wt,
    const float* __restrict__ bias, const float* __restrict__ alpha, void* __restrict__ outv,
    int npix, int cout, size_t in_bstride, size_t out_bstride, int rs_in, int rs_out){
  __shared__ float Wl[64*64];
  __shared__ float it[64][64];
  int b = blockIdx.y;
  int n0 = blockIdx.x * 64;
  int tid = threadIdx.x;
  const bf16* ib = in + (size_t)b * in_bstride;
  for (int i = tid; i < cout * 64; i += 256) Wl[i] = Wt[i];
  for (int i = tid; i < 64 * 64; i += 256){
    int ci = i >> 6, nn = i & 63;
    int n = n0 + nn;
    it[ci][nn] = (n < npix) ? b2f(ib[(size_t)ci * rs_in + n]) : 0.f;
  }
  __syncthreads();
  float al = alpha[0];
  for (int oi = tid; oi < cout * 64; oi += 256){
    int co = oi >> 6, nn = oi & 63;
    float acc = bias[co];
    #pragma unroll
    for (int ci = 0; ci < 64; ci++) acc = fmaf(Wl[co*64+ci], it[ci][nn], acc);
    acc = acc >= 0.f ? acc : al * acc;
    int n = n0 + nn;
    if (n < npix){
      size_t idx = (size_t)b * out_bstride + (size_t)co * rs_out + n;
      if constexpr (OB) ((bf16*)outv)[idx] = __float2bfloat16(acc);
      else              ((float*)outv)[idx] = acc;
    }
  }
}

// 1/max(||mat patch||,1e-4) per (b,n)
__global__ __launch_bounds__(256) void k_norminv(const float* __restrict__ mat, float* __restrict__ ninv){
  int id = blockIdx.x * 256 + threadIdx.x;
  if (id >= NB * NP) return;
  int b = id / NP, n = id - b * NP;
  int off, d, y, x; n_decode(n, off, d, y, x);
  const float* mp = mat + (size_t)b * 32 * NP + off;
  float s = 0.f;
  for (int c = 0; c < 32; c++){
    const float* pc = mp + (size_t)c * NP;
    #pragma unroll
    for (int dy = -1; dy <= 1; dy++){
      int yy = y + dy; if (yy < 0 || yy >= d) continue;
      #pragma unroll
      for (int dx = -1; dx <= 1; dx++){
        int xx = x + dx; if (xx < 0 || xx >= d) continue;
        float v = pc[yy * d + xx]; s += v * v;
      }
    }
  }
  ninv[id] = 1.f / fmaxf(sqrtf(s), 1e-4f);
}

// unfold match_base -> U[b][2304][288] bf16
__global__ __launch_bounds__(256) void k_packU(const float* __restrict__ mb, bf16* __restrict__ U){
  int id = blockIdx.x * 256 + threadIdx.x;
  if (id >= NB * HW * 288) return;
  int b = id / (HW*288), rem = id - b*(HW*288);
  int p = rem / 288, k = rem - p * 288;
  int c = k / 9, r = k - c * 9, kh = r / 3, kw = r - kh * 3;
  int y = p / 48 + kh - 1, x = (p % 48) + kw - 1;
  float v = 0.f;
  if (y >= 0 && y < 48 && x >= 0 && x < 48)
    v = mb[((size_t)b * 32 + c) * HW + y * 48 + x];
  U[id] = __float2bfloat16(v);
}

// unfold mat * (10*ninv) -> Wp[g][NPAD][288] bf16 (group-local)
__global__ __launch_bounds__(256) void k_packW(const float* __restrict__ mat, const float* __restrict__ ninv,
                                               bf16* __restrict__ Wp, int b0, int g){
  int id = blockIdx.x * 256 + threadIdx.x;
  if (id >= g * NPAD * 288) return;
  int bg = id / (NPAD*288), rem = id - bg*(NPAD*288);
  int n = rem / 288, k = rem - n * 288;
  float v = 0.f;
  if (n < NP){
    int b = b0 + bg;
    int c = k / 9, r = k - c * 9, kh = r / 3, kw = r - kh * 3;
    int off, d, y, x; n_decode(n, off, d, y, x);
    int yy = y + kh - 1, xx = x + kw - 1;
    if (yy >= 0 && yy < d && xx >= 0 && xx < d)
      v = mat[((size_t)b * 32 + c) * NP + off + yy * d + xx] * 10.f * ninv[(size_t)b*NP + n];
  }
  Wp[id] = __float2bfloat16(v);
}

// unfold base (bf16) -> RpT[b][t][576][32] bf16 (j-major, k-minor within tile)
__global__ __launch_bounds__(256) void k_packR(const bf16* __restrict__ src, bf16* __restrict__ dst){
  int id = blockIdx.x * 256 + threadIdx.x;
  if (id >= NB * NT * 576 * 32) return;
  int b = id / (NT*576*32), rem = id - b*(NT*576*32);
  int t = rem / (576*32), rem2 = rem - t*(576*32);
  int j = rem2 / 32, kl = rem2 - j*32;
  int n = t*32 + kl;
  bf16 v = __float2bfloat16(0.f);
  if (n < NP){
    int c = j / 9, r = j - c * 9, kh = r / 3, kw = r - kh * 3;
    int off, d, y, x; n_decode(n, off, d, y, x);
    int yy = y + kh - 1, xx = x + kw - 1;
    if (yy >= 0 && yy < d && xx >= 0 && xx < d)
      v = src[((size_t)b * 64 + c) * NP + off + yy * d + xx];
  }
  dst[id] = v;
}

// GEMM1: S[bg][m][n] = dot(U[m,:288], Wp[n,:288]) fp16; 128x128 tile, 8 waves
__global__ __launch_bounds__(512) void k_gemm1m(const bf16* __restrict__ U, const bf16* __restrict__ Wp,
                                                __half* __restrict__ S16, int b0){
  int bg = blockIdx.z, b = b0 + bg;
  int m0 = blockIdx.y * 128, n0 = blockIdx.x * 128;
  int tid = threadIdx.x, l = tid & 63, w = tid >> 6;
  int wm = w >> 1, wn = w & 1;
  __shared__ __align__(16) char At[8192];
  __shared__ __align__(16) char Bt[8192];
  f32x4 acc[2][4] = {};
  const bf16* Ub = U + ((size_t)b * HW + m0) * 288;
  const bf16* Wb = Wp + ((size_t)bg * NPAD + n0) * 288;
  int srow = tid >> 2, scs = (tid & 3) ^ (srow & 3);
  int ch = l >> 4;
  int abyte[2], bbyte[4];
  #pragma unroll
  for (int mt = 0; mt < 2; mt++){
    int lr = wm*32 + mt*16 + (l&15);
    abyte[mt] = lr*64 + ((ch ^ (lr&3))<<4);
  }
  #pragma unroll
  for (int nt = 0; nt < 4; nt++){
    int lr = wn*64 + nt*16 + (l&15);
    bbyte[nt] = lr*64 + ((ch ^ (lr&3))<<4);
  }
  for (int k0 = 0; k0 < 288; k0 += 32){
    gl16(Ub + (size_t)srow*288 + k0 + scs*8, At + tid*16);
    gl16(Wb + (size_t)srow*288 + k0 + scs*8, Bt + tid*16);
    __syncthreads();
    short8 a[2], bv[4];
    #pragma unroll
    for (int mt = 0; mt < 2; mt++) a[mt] = *reinterpret_cast<const short8*>(At + abyte[mt]);
    #pragma unroll
    for (int nt = 0; nt < 4; nt++) bv[nt] = *reinterpret_cast<const short8*>(Bt + bbyte[nt]);
    #pragma unroll
    for (int mt = 0; mt < 2; mt++)
      #pragma unroll
      for (int nt = 0; nt < 4; nt++)
        acc[mt][nt] = __builtin_amdgcn_mfma_f32_16x16x32_bf16(a[mt], bv[nt], acc[mt][nt], 0, 0, 0);
    __syncthreads();
  }
  #pragma unroll
  for (int mt = 0; mt < 2; mt++){
    #pragma unroll
    for (int nt = 0; nt < 4; nt++){
      #pragma unroll
      for (int i = 0; i < 4; i++){
        int gm = m0 + wm*32 + mt*16 + (l>>4)*4 + i;
        int gn = n0 + wn*64 + nt*16 + (l&15);
        float s = acc[mt][nt][i];
        if (gn >= NP) s = -60000.f;
        S16[((size_t)bg*HW + gm)*SW2 + gn] = __float2half(s);
      }
    }
  }
}

__device__ __forceinline__ float wredmax(float v){
  #pragma unroll
  for (int o = 1; o < 64; o <<= 1) v = fmaxf(v, __shfl_xor(v, o));
  return v;
}
__device__ __forceinline__ float wredsum(float v){
  #pragma unroll
  for (int o = 1; o < 64; o <<= 1) v += __shfl_xor(v, o);
  return v;
}

// row stats: mrow = max, rsi = 1/sum(exp(s-m)); global-batch outputs
__global__ __launch_bounds__(256) void k_stats(const __half* __restrict__ S16, float* __restrict__ mrow,
                                               float* __restrict__ rsi, int b0){
  int bg = blockIdx.y, b = b0 + bg, p = blockIdx.x;
  const __half* row = S16 + ((size_t)bg*HW + p)*SW2;
  int tid = threadIdx.x;
  __shared__ float wrm[4], wrs[4];
  float m = -3e38f;
  for (int i = tid; i < SW2/8; i += 256){
    f16x8 v = *reinterpret_cast<const f16x8*>(row + i*8);
    #pragma unroll
    for (int j = 0; j < 8; j++) m = fmaxf(m, (float)v[j]);
  }
  m = wredmax(m);
  if ((tid & 63) == 0) wrm[tid >> 6] = m;
  __syncthreads();
  m = fmaxf(fmaxf(wrm[0], wrm[1]), fmaxf(wrm[2], wrm[3]));
  float s = 0.f;
  for (int i = tid; i < SW2/8; i += 256){
    f16x8 v = *reinterpret_cast<const f16x8*>(row + i*8);
    #pragma unroll
    for (int j = 0; j < 8; j++) s += __expf((float)v[j] - m);
  }
  s = wredsum(s);
  if ((tid & 63) == 0) wrs[tid >> 6] = s;
  __syncthreads();
  if (tid == 0){
    mrow[(size_t)b*HW + p] = m;
    rsi [(size_t)b*HW + p] = 1.f / (wrs[0] + wrs[1] + wrs[2] + wrs[3]);
  }
}

// GEMM2: T[b][m][j] = sum_k exp(S[m][k]-mrow)*rsi * RpT[k][j]; BM=64, BN=96
__global__ __launch_bounds__(512) void k_gemm2m(const __half* __restrict__ S16, const bf16* __restrict__ RpT,
    const float* __restrict__ mrow, const float* __restrict__ rsi, __half* __restrict__ T, int b0){
  int bg = blockIdx.z, b = b0 + bg;
  int m0 = blockIdx.y * 64;
  int jh = blockIdx.x;                 // 0..5 -> 96-col group
  int tid = threadIdx.x, l = tid & 63, w = tid >> 6;
  int wm = w >> 1, wc = w & 1;         // wm: m-tile 0..3, wc: 48-col half 0..1
  __shared__ __align__(16) char Ss[4096];     // [64][32] fp16
  __shared__ __align__(16) char Rt[6144];     // [96][32] bf16
  __shared__ float ml[64], rl[64];
  if (tid < 64){
    ml[tid] = mrow[(size_t)b*HW + m0 + tid];
    rl[tid] = rsi [(size_t)b*HW + m0 + tid];
  }
  __syncthreads();
  int arow = wm*16 + (l&15);
  float mr = ml[arow], rr = rl[arow];
  int ch = l >> 4;
  int abyte = arow*64 + ((ch ^ (arow&3))<<4);
  int rbyte[3];
  #pragma unroll
  for (int ci = 0; ci < 3; ci++){
    int rloc = wc*48 + ci*16 + (l&15);
    rbyte[ci] = rloc*64 + ((ch ^ (rloc&3))<<4);
  }
  f32x4 acc[3] = {};
  const __half* Sb = S16 + ((size_t)bg*HW + m0)*SW2;
  for (int t = 0; t < NT; t++){
    if (tid < 256){
      int row = tid >> 2, cs = (tid & 3) ^ (row & 3);
      gl16(Sb + (size_t)row*SW2 + t*32 + cs*8, Ss + tid*16);
    }
    if (tid < 384){
      int row = tid >> 2, cs = (tid & 3) ^ (row & 3);
      const bf16* Rb = RpT + (((size_t)b*NT + t)*576 + jh*96)*32;
      gl16(Rb + (size_t)row*32 + cs*8, Rt + tid*16);
    }
    __syncthreads();
    f16x8 sv = *reinterpret_cast<const f16x8*>(Ss + abyte);
    short8 pa;
    #pragma unroll
    for (int i = 0; i < 8; i++)
      pa[i] = f2bs(__expf((float)sv[i] - mr) * rr);
    #pragma unroll
    for (int ci = 0; ci < 3; ci++){
      short8 bv = *reinterpret_cast<const short8*>(Rt + rbyte[ci]);
      acc[ci] = __builtin_amdgcn_mfma_f32_16x16x32_bf16(pa, bv, acc[ci], 0, 0, 0);
    }
    __syncthreads();
  }
  #pragma unroll
  for (int ci = 0; ci < 3; ci++){
    #pragma unroll
    for (int i = 0; i < 4; i++){
      int gm = m0 + wm*16 + (l>>4)*4 + i;
      int gc = jh*96 + wc*48 + ci*16 + (l&15);
      T[((size_t)b*HW + gm)*576 + gc] = __float2half(acc[ci][i]);
    }
  }
}

// out[b,co,y,x] = x + 0.25 * fold(T); output dtype per flag (0=f32, 1=bf16)
__global__ __launch_bounds__(256) void k_fold(const __half* __restrict__ T, const float* __restrict__ x,
    void* __restrict__ out, const int* __restrict__ flag){
  int id = blockIdx.x * 256 + threadIdx.x;
  if (id >= NB * 64 * HW) return;
  int b = id / (64*HW), id2 = id - b*(64*HW);
  int co = id2 / HW, p = id2 - co * HW;
  int y = p / 48, xx = p - y * 48;
  float acc = 0.f;
  #pragma unroll
  for (int dy = -1; dy <= 1; dy++){
    int yy = y + dy; if (yy < 0 || yy >= 48) continue;
    #pragma unroll
    for (int dx = -1; dx <= 1; dx++){
      int x2 = xx + dx; if (x2 < 0 || x2 >= 48) continue;
      acc += (float)T[((size_t)b*HW + yy*48 + x2) * 576 + co*9 + (1-dy)*3 + (1-dx)];
    }
  }
  size_t gi = (size_t)id;
  float r = x[gi] + 0.25f * acc;
  if (flag[0]) ((bf16*)out)[gi] = __float2bfloat16(r);
  else         ((float*)out)[gi] = r;
}

extern "C" void kernel_launch(void* const* d_in, const int* in_sizes, int n_in,
                              void* d_out, int out_size, void* d_ws, size_t ws_size,
                              hipStream_t stream){
  (void)out_size; (void)n_in;

  char* cur = (char*)d_ws;
  auto carve = [&](size_t bytes)->char*{
    char* p = cur; cur += (bytes + 255) & ~(size_t)255; return p;
  };
  int*   flag  = (int*)  carve(4);
  float* canon[10];
  for (int i = 0; i < 10; i++) canon[i] = (float*)carve((size_t)in_sizes[i] * 4);
  float* xc = canon[0];
  float* Wb = canon[1]; float* bb = canon[2]; float* ab = canon[3];
  float* Wm = canon[4]; float* bm = canon[5]; float* am = canon[6];
  float* Wa = canon[7]; float* ba = canon[8]; float* aa = canon[9];

  bf16*  xs    = (bf16*) carve((size_t)NB * 64 * NP * 2);
  float* mbuf  = (float*)carve((size_t)NB * 32 * HW * 4);
  float* mat   = (float*)carve((size_t)NB * 32 * NP * 4);
  float* ninv  = (float*)carve((size_t)NB * NP * 4);
  bf16*  baseh = (bf16*) carve((size_t)NB * 64 * NP * 2);
  bf16*  U     = (bf16*) carve((size_t)NB * HW * 288 * 2);
  bf16*  RpT   = (bf16*) carve((size_t)NB * NT * 576 * 32 * 2);
  __half* T    = (__half*)carve((size_t)NB * HW * 576 * 2);
  float* mrow  = (float*)carve((size_t)NB * HW * 4);
  float* rsi   = (float*)carve((size_t)NB * HW * 4);

  size_t fixed = (size_t)(cur - (char*)d_ws);
  size_t perb  = ((size_t)NPAD*288*2 + 255 & ~(size_t)255) + ((size_t)HW*SW2*2 + 255 & ~(size_t)255);
  size_t avail = (ws_size > fixed) ? ws_size - fixed : 0;
  int g = (int)(avail / perb);
  if (g < 1) g = 1;
  if (g > NB) g = NB;
  bf16*  Wp  = (bf16*) carve((size_t)g * NPAD * 288 * 2);
  __half* S16 = (__half*)carve((size_t)g * HW * SW2 * 2);

  k_detect<<<1, 256, 0, stream>>>(d_in[0], flag);
  for (int i = 0; i < 10; i++)
    k_canon<<<(in_sizes[i] + 255)/256, 256, 0, stream>>>(d_in[i], canon[i], in_sizes[i], flag);

  k_resize<<<(NB*NP + 255)/256, 256, 0, stream>>>(xc, xs);

  dim3 gm((NP + 63)/64, NB);
  k_conv1x1<false><<<gm, 256, 0, stream>>>(xs, Wm, bm, am, (void*)mat,   NP, 32, (size_t)64*NP, (size_t)32*NP, NP, NP);
  k_conv1x1<true ><<<gm, 256, 0, stream>>>(xs, Wa, ba, aa, (void*)baseh, NP, 64, (size_t)64*NP, (size_t)64*NP, NP, NP);
  dim3 gb((HW + 63)/64, NB);
  k_conv1x1<false><<<gb, 256, 0, stream>>>(xs, Wb, bb, ab, (void*)mbuf,  HW, 32, (size_t)64*NP, (size_t)32*HW, NP, HW);

  k_norminv<<<(NB*NP + 255)/256, 256, 0, stream>>>(mat, ninv);
  k_packU<<<((size_t)NB*HW*288 + 255)/256, 256, 0, stream>>>(mbuf, U);
  k_packR<<<((size_t)NB*NT*576*32 + 255)/256, 256, 0, stream>>>(baseh, RpT);

  for (int b0 = 0; b0 < NB; b0 += g){
    int gc = (b0 + g <= NB) ? g : (NB - b0);
    k_packW<<<((size_t)gc*NPAD*288 + 255)/256, 256, 0, stream>>>(mat, ninv, Wp, b0, gc);
    dim3 g1(NPAD/128, HW/128, gc);
    k_gemm1m<<<g1, 512, 0, stream>>>(U, Wp, S16, b0);
    dim3 gs(HW, gc);
    k_stats<<<gs, 256, 0, stream>>>(S16, mrow, rsi, b0);
    dim3 g2(6, HW/64, gc);
    k_gemm2m<<<g2, 512, 0, stream>>>(S16, RpT, mrow, rsi, T, b0);
  }

  k_fold<<<(NB*64*HW + 255)/256, 256, 0, stream>>>(T, xc, d_out, flag);
}

// Round 5
// 600.881 us; speedup vs baseline: 6.0074x; 1.0976x over previous
//
#include <hip/hip_runtime.h>
#include <hip/hip_bf16.h>
#include <hip/hip_fp16.h>

typedef __half h16;
typedef _Float16 f16;
typedef f16 f16x8 __attribute__((ext_vector_type(8)));
typedef __attribute__((ext_vector_type(4))) float f32x4;

#define NB 4
#define NCH 64
#define HW 2304      // 48*48
#define NP 7470      // total patches across 5 scales
#define NPAD 7552    // 59*128 = 236*32
#define NT 236       // k-tiles of 32
#define NBLK 59      // 128-col blocks
#define SW2 NPAD

__device__ __forceinline__ float us2f(unsigned short u){
  unsigned v = (unsigned)u << 16; float f; __builtin_memcpy(&f, &v, 4); return f;
}
__device__ __forceinline__ void gl16(const void* g, void* l){
  __builtin_amdgcn_global_load_lds((const __attribute__((address_space(1))) unsigned int*)g,
                                   (__attribute__((address_space(3))) unsigned int*)l, 16, 0, 0);
}

// n -> (scale offset, dim, y, x). dims 48,43,38,33,28; offsets 0,2304,4153,5597,6686
__device__ __forceinline__ void n_decode(int n, int& off, int& d, int& y, int& x){
  if (n < 2304)      { off = 0;    d = 48; }
  else if (n < 4153) { off = 2304; d = 43; }
  else if (n < 5597) { off = 4153; d = 38; }
  else if (n < 6686) { off = 5597; d = 33; }
  else               { off = 6686; d = 28; }
  int l = n - off; y = l / d; x = l - y * d;
}

// ---- dtype probe (proven R3/R4) ----
__global__ __launch_bounds__(256) void k_detect(const void* __restrict__ x, int* __restrict__ flag){
  const unsigned short* u = (const unsigned short*)x;
  int tid = threadIdx.x;
  int c = 0;
  for (int i = tid; i < 8192; i += 256){
    float v = us2f(u[i]);
    float a = fabsf(v);
    if (v == 0.f || (a > 1e-5f && a < 1e3f)) c++;
  }
  #pragma unroll
  for (int o = 1; o < 64; o <<= 1) c += __shfl_xor(c, o);
  __shared__ int wr[4];
  if ((tid & 63) == 0) wr[tid >> 6] = c;
  __syncthreads();
  if (tid == 0) flag[0] = ((wr[0]+wr[1]+wr[2]+wr[3]) > 7000) ? 1 : 0;
}

struct CanonArgs { const void* src[10]; float* dst[10]; int end[10]; };

__global__ __launch_bounds__(256) void k_canon_all(CanonArgs a, int tot, const int* __restrict__ flag){
  int id = blockIdx.x * 256 + threadIdx.x;
  if (id >= tot) return;
  int k = 0;
  while (id >= a.end[k]) k++;
  int local = id - (k ? a.end[k-1] : 0);
  float v;
  if (flag[0]) v = us2f(((const unsigned short*)a.src[k])[local]);
  else         v = ((const float*)a.src[k])[local];
  a.dst[k][local] = v;
}

// Bilinear resize (half-pixel, antialias=False): x fp32 -> xs f16 [b][c][n]
__global__ __launch_bounds__(256) void k_resize(const float* __restrict__ x, h16* __restrict__ xs){
  int id = blockIdx.x * 256 + threadIdx.x;
  if (id >= NB * NP) return;
  int b = id / NP, n = id - b * NP;
  int off, d, y, xx; n_decode(n, off, d, y, xx);
  const float* xb = x + (size_t)b * NCH * HW;
  h16* o = xs + (size_t)b * NCH * NP + n;
  if (off == 0){
    int p = y * 48 + xx;
    for (int c = 0; c < NCH; c++) o[(size_t)c * NP] = __float2half(xb[c * HW + p]);
  } else {
    float cy = (y + 0.5f) * (48.0f / (float)d) - 0.5f;
    float cx = (xx + 0.5f) * (48.0f / (float)d) - 0.5f;
    int y0 = (int)floorf(cy), x0 = (int)floorf(cx);
    float fy = cy - (float)y0, fx = cx - (float)x0;
    int y1 = min(y0 + 1, 47), x1 = min(x0 + 1, 47);
    y0 = max(y0, 0); x0 = max(x0, 0);
    float w00 = (1.f-fy)*(1.f-fx), w01 = (1.f-fy)*fx, w10 = fy*(1.f-fx), w11 = fy*fx;
    for (int c = 0; c < NCH; c++){
      const float* pc = xb + c * HW;
      float v = w00 * pc[y0*48+x0] + w01 * pc[y0*48+x1]
              + w10 * pc[y1*48+x0] + w11 * pc[y1*48+x1];
      o[(size_t)c * NP] = __float2half(v);
    }
  }
}

// 1x1 conv (Cin=64) + PReLU; in f16 [64][rs_in]; out fp32 or f16.
template<bool OB>
__global__ __launch_bounds__(256) void k_conv1x1(const h16* __restrict__ in, const float* __restrict__ Wt,
    const float* __restrict__ bias, const float* __restrict__ alpha, void* __restrict__ outv,
    int npix, int cout, size_t in_bstride, size_t out_bstride, int rs_in, int rs_out){
  __shared__ float Wl[64*64];
  __shared__ float it[64][64];
  int b = blockIdx.y;
  int n0 = blockIdx.x * 64;
  int tid = threadIdx.x;
  const h16* ib = in + (size_t)b * in_bstride;
  for (int i = tid; i < cout * 64; i += 256) Wl[i] = Wt[i];
  for (int i = tid; i < 64 * 64; i += 256){
    int ci = i >> 6, nn = i & 63;
    int n = n0 + nn;
    it[ci][nn] = (n < npix) ? __half2float(ib[(size_t)ci * rs_in + n]) : 0.f;
  }
  __syncthreads();
  float al = alpha[0];
  for (int oi = tid; oi < cout * 64; oi += 256){
    int co = oi >> 6, nn = oi & 63;
    float acc = bias[co];
    #pragma unroll
    for (int ci = 0; ci < 64; ci++) acc = fmaf(Wl[co*64+ci], it[ci][nn], acc);
    acc = acc >= 0.f ? acc : al * acc;
    int n = n0 + nn;
    if (n < npix){
      size_t idx = (size_t)b * out_bstride + (size_t)co * rs_out + n;
      if constexpr (OB) ((h16*)outv)[idx] = __float2half(acc);
      else              ((float*)outv)[idx] = acc;
    }
  }
}

// 1/max(||mat patch||,1e-4) per (b,n)
__global__ __launch_bounds__(256) void k_norminv(const float* __restrict__ mat, float* __restrict__ ninv){
  int id = blockIdx.x * 256 + threadIdx.x;
  if (id >= NB * NP) return;
  int b = id / NP, n = id - b * NP;
  int off, d, y, x; n_decode(n, off, d, y, x);
  const float* mp = mat + (size_t)b * 32 * NP + off;
  float s = 0.f;
  for (int c = 0; c < 32; c++){
    const float* pc = mp + (size_t)c * NP;
    #pragma unroll
    for (int dy = -1; dy <= 1; dy++){
      int yy = y + dy; if (yy < 0 || yy >= d) continue;
      #pragma unroll
      for (int dx = -1; dx <= 1; dx++){
        int xx = x + dx; if (xx < 0 || xx >= d) continue;
        float v = pc[yy * d + xx]; s += v * v;
      }
    }
  }
  ninv[id] = 1.f / fmaxf(sqrtf(s), 1e-4f);
}

// unfold match_base -> U[b][2304][288] f16
__global__ __launch_bounds__(256) void k_packU(const float* __restrict__ mb, h16* __restrict__ U){
  int id = blockIdx.x * 256 + threadIdx.x;
  if (id >= NB * HW * 288) return;
  int b = id / (HW*288), rem = id - b*(HW*288);
  int p = rem / 288, k = rem - p * 288;
  int c = k / 9, r = k - c * 9, kh = r / 3, kw = r - kh * 3;
  int y = p / 48 + kh - 1, x = (p % 48) + kw - 1;
  float v = 0.f;
  if (y >= 0 && y < 48 && x >= 0 && x < 48)
    v = mb[((size_t)b * 32 + c) * HW + y * 48 + x];
  U[id] = __float2half(v);
}

// unfold mat * (10*ninv) -> Wp[g][NPAD][288] f16
__global__ __launch_bounds__(256) void k_packW(const float* __restrict__ mat, const float* __restrict__ ninv,
                                               h16* __restrict__ Wp, int b0, int g){
  int id = blockIdx.x * 256 + threadIdx.x;
  if (id >= g * NPAD * 288) return;
  int bg = id / (NPAD*288), rem = id - bg*(NPAD*288);
  int n = rem / 288, k = rem - n * 288;
  float v = 0.f;
  if (n < NP){
    int b = b0 + bg;
    int c = k / 9, r = k - c * 9, kh = r / 3, kw = r - kh * 3;
    int off, d, y, x; n_decode(n, off, d, y, x);
    int yy = y + kh - 1, xx = x + kw - 1;
    if (yy >= 0 && yy < d && xx >= 0 && xx < d)
      v = mat[((size_t)b * 32 + c) * NP + off + yy * d + xx] * 10.f * ninv[(size_t)b*NP + n];
  }
  Wp[id] = __float2half(v);
}

// unfold base (f16) -> RpT[b][t][576][32] f16
__global__ __launch_bounds__(256) void k_packR(const h16* __restrict__ src, h16* __restrict__ dst){
  int id = blockIdx.x * 256 + threadIdx.x;
  if (id >= NB * NT * 576 * 32) return;
  int b = id / (NT*576*32), rem = id - b*(NT*576*32);
  int t = rem / (576*32), rem2 = rem - t*(576*32);
  int j = rem2 / 32, kl = rem2 - j*32;
  int n = t*32 + kl;
  h16 v = __float2half(0.f);
  if (n < NP){
    int c = j / 9, r = j - c * 9, kh = r / 3, kw = r - kh * 3;
    int off, d, y, x; n_decode(n, off, d, y, x);
    int yy = y + kh - 1, xx = x + kw - 1;
    if (yy >= 0 && yy < d && xx >= 0 && xx < d)
      v = src[((size_t)b * 64 + c) * NP + off + yy * d + xx];
  }
  dst[id] = v;
}

// GEMM1 + fused block-local softmax stats.
// S16[bg][m][n] = exp(s - Mloc) fp16 (pad->0); Pm/Ps[bg][nblk][m] = Mloc, sum.
__global__ __launch_bounds__(512) void k_gemm1m(const f16* __restrict__ U, const f16* __restrict__ Wp,
    h16* __restrict__ S16, float* __restrict__ Pm, float* __restrict__ Ps, int b0){
  int bg = blockIdx.z, b = b0 + bg;
  int m0 = blockIdx.y * 128, n0 = blockIdx.x * 128;
  int tid = threadIdx.x, l = tid & 63, w = tid >> 6;
  int wm = w >> 1, wn = w & 1;
  int ch = l >> 4, cl = l & 15;
  __shared__ __align__(16) char At[8192];
  __shared__ __align__(16) char Bt[8192];
  __shared__ float mred[128][2];
  __shared__ float sred[128][2];
  f32x4 acc[2][4] = {};
  const f16* Ub = U + ((size_t)b * HW + m0) * 288;
  const f16* Wb = Wp + ((size_t)bg * NPAD + n0) * 288;
  int srow = tid >> 2, scs = (tid & 3) ^ (srow & 3);
  int abyte[2], bbyte[4];
  #pragma unroll
  for (int mt = 0; mt < 2; mt++){
    int lr = wm*32 + mt*16 + cl;
    abyte[mt] = lr*64 + ((ch ^ (lr&3))<<4);
  }
  #pragma unroll
  for (int nt = 0; nt < 4; nt++){
    int lr = wn*64 + nt*16 + cl;
    bbyte[nt] = lr*64 + ((ch ^ (lr&3))<<4);
  }
  for (int k0 = 0; k0 < 288; k0 += 32){
    gl16(Ub + (size_t)srow*288 + k0 + scs*8, At + tid*16);
    gl16(Wb + (size_t)srow*288 + k0 + scs*8, Bt + tid*16);
    __syncthreads();
    f16x8 a[2], bv[4];
    #pragma unroll
    for (int mt = 0; mt < 2; mt++) a[mt] = *reinterpret_cast<const f16x8*>(At + abyte[mt]);
    #pragma unroll
    for (int nt = 0; nt < 4; nt++) bv[nt] = *reinterpret_cast<const f16x8*>(Bt + bbyte[nt]);
    #pragma unroll
    for (int mt = 0; mt < 2; mt++)
      #pragma unroll
      for (int nt = 0; nt < 4; nt++)
        acc[mt][nt] = __builtin_amdgcn_mfma_f32_16x16x32_f16(a[mt], bv[nt], acc[mt][nt], 0, 0, 0);
    __syncthreads();
  }
  // block-local row max over 128 cols
  #pragma unroll
  for (int mt = 0; mt < 2; mt++)
    #pragma unroll
    for (int i = 0; i < 4; i++){
      float v = -3e38f;
      #pragma unroll
      for (int nt = 0; nt < 4; nt++){
        int gn = n0 + wn*64 + nt*16 + cl;
        float t = acc[mt][nt][i];
        v = fmaxf(v, (gn < NP) ? t : -3e38f);
      }
      v = fmaxf(v, __shfl_xor(v, 1));
      v = fmaxf(v, __shfl_xor(v, 2));
      v = fmaxf(v, __shfl_xor(v, 4));
      v = fmaxf(v, __shfl_xor(v, 8));
      if (cl == 0) mred[wm*32 + mt*16 + ch*4 + i][wn] = v;
    }
  __syncthreads();
  // exp, write S16, row sums
  #pragma unroll
  for (int mt = 0; mt < 2; mt++)
    #pragma unroll
    for (int i = 0; i < 4; i++){
      int r = wm*32 + mt*16 + ch*4 + i;
      float Ml = fmaxf(mred[r][0], mred[r][1]);
      int gm = m0 + r;
      float s = 0.f;
      #pragma unroll
      for (int nt = 0; nt < 4; nt++){
        int gn = n0 + wn*64 + nt*16 + cl;
        float e = (gn < NP) ? __expf(acc[mt][nt][i] - Ml) : 0.f;
        S16[((size_t)bg*HW + gm)*SW2 + gn] = __float2half(e);
        s += e;
      }
      s += __shfl_xor(s, 1);
      s += __shfl_xor(s, 2);
      s += __shfl_xor(s, 4);
      s += __shfl_xor(s, 8);
      if (cl == 0) sred[r][wn] = s;
    }
  __syncthreads();
  if (tid < 128){
    float Mf = fmaxf(mred[tid][0], mred[tid][1]);
    float L  = sred[tid][0] + sred[tid][1];
    size_t o = ((size_t)bg*NBLK + blockIdx.x)*HW + m0 + tid;
    Pm[o] = Mf; Ps[o] = L;
  }
}

// combine partials: Fac[bg][nblk][row] = exp(Mloc - Mglob) / L_glob
__global__ __launch_bounds__(256) void k_sfac(const float* __restrict__ Pm, const float* __restrict__ Ps,
                                              float* __restrict__ Fac, int gc){
  int id = blockIdx.x * 256 + threadIdx.x;
  if (id >= gc * HW) return;
  int bg = id / HW, r = id - bg * HW;
  const float* pm = Pm + (size_t)bg*NBLK*HW + r;
  const float* ps = Ps + (size_t)bg*NBLK*HW + r;
  float M = -3e38f;
  for (int k = 0; k < NBLK; k++) M = fmaxf(M, pm[(size_t)k*HW]);
  float L = 0.f;
  for (int k = 0; k < NBLK; k++) L += __expf(pm[(size_t)k*HW] - M) * ps[(size_t)k*HW];
  float inv = 1.f / L;
  float* fo = Fac + (size_t)bg*NBLK*HW + r;
  for (int k = 0; k < NBLK; k++) fo[(size_t)k*HW] = __expf(pm[(size_t)k*HW] - M) * inv;
}

// GEMM2: T[b][m][j] = sum_k (S16[m][k]*Fac) * RpT[k][j]
// BM=128, BN=192, 384 thr (6 waves = 2 wm x 3 wc), wave = 4x4 16x16x32 frags.
__global__ __launch_bounds__(384) void k_gemm2n(const h16* __restrict__ S16h, const h16* __restrict__ RpTh,
    const float* __restrict__ Fac, h16* __restrict__ T, int b0){
  const f16* S16 = (const f16*)S16h;
  const f16* RpT = (const f16*)RpTh;
  int bg = blockIdx.z, b = b0 + bg;
  int m0 = blockIdx.y * 128;
  int jh = blockIdx.x;                  // 0..2 -> 192-col group
  int tid = threadIdx.x, l = tid & 63, w = tid >> 6;
  int wm = w / 3, wc = w % 3;
  int ch = l >> 4, cl = l & 15;
  __shared__ __align__(16) char Ss[8192];   // [128][32] f16, xor-4 swizzled
  __shared__ __align__(16) char Rt[12288];  // [192][32] f16, xor-4 swizzled
  f32x4 acc[4][4] = {};
  int abyte[4], rbyte[4], frow[4];
  #pragma unroll
  for (int mt = 0; mt < 4; mt++){
    int lr = wm*64 + mt*16 + cl;
    frow[mt] = m0 + lr;
    abyte[mt] = lr*64 + ((ch ^ (lr&3))<<4);
  }
  #pragma unroll
  for (int nt = 0; nt < 4; nt++){
    int jr = wc*64 + nt*16 + cl;
    rbyte[nt] = jr*64 + ((ch ^ (jr&3))<<4);
  }
  const f16* Sb = S16 + ((size_t)bg*HW + m0)*SW2;
  const f16* Rb0 = RpT + (size_t)b*NT*576*32 + (size_t)jh*192*32;
  const float* facb = Fac + (size_t)bg*NBLK*HW;
  for (int nb = 0; nb < NBLK; nb++){
    f16 facs[4];
    #pragma unroll
    for (int mt = 0; mt < 4; mt++)
      facs[mt] = (f16)facb[(size_t)nb*HW + frow[mt]];
    #pragma unroll 1
    for (int tt = 0; tt < 4; tt++){
      int t = nb*4 + tt;
      // stage S tile [128][32]: 512 x 16B
      for (int i = tid; i < 512; i += 384){
        int row = i >> 2, c = (i & 3) ^ (row & 3);
        gl16(Sb + (size_t)row*SW2 + t*32 + c*8, Ss + i*16);
      }
      // stage R tile [192][32]: 768 x 16B
      {
        const f16* Rb = Rb0 + (size_t)t*(576*32);
        for (int i = tid; i < 768; i += 384){
          int row = i >> 2, c = (i & 3) ^ (row & 3);
          gl16(Rb + (size_t)row*32 + c*8, Rt + i*16);
        }
      }
      __syncthreads();
      f16x8 pa[4], bv[4];
      #pragma unroll
      for (int mt = 0; mt < 4; mt++){
        f16x8 sv = *reinterpret_cast<const f16x8*>(Ss + abyte[mt]);
        pa[mt] = sv * facs[mt];
      }
      #pragma unroll
      for (int nt = 0; nt < 4; nt++) bv[nt] = *reinterpret_cast<const f16x8*>(Rt + rbyte[nt]);
      #pragma unroll
      for (int mt = 0; mt < 4; mt++)
        #pragma unroll
        for (int nt = 0; nt < 4; nt++)
          acc[mt][nt] = __builtin_amdgcn_mfma_f32_16x16x32_f16(pa[mt], bv[nt], acc[mt][nt], 0, 0, 0);
      __syncthreads();
    }
  }
  #pragma unroll
  for (int mt = 0; mt < 4; mt++)
    #pragma unroll
    for (int nt = 0; nt < 4; nt++)
      #pragma unroll
      for (int i = 0; i < 4; i++){
        int gm = m0 + wm*64 + mt*16 + ch*4 + i;
        int gc = jh*192 + wc*64 + nt*16 + cl;
        T[((size_t)b*HW + gm)*576 + gc] = __float2half(acc[mt][nt][i]);
      }
}

// out[b,co,y,x] = x + 0.25 * fold(T); output dtype per flag (0=f32, 1=bf16)
__global__ __launch_bounds__(256) void k_fold(const h16* __restrict__ T, const float* __restrict__ x,
    void* __restrict__ out, const int* __restrict__ flag){
  int id = blockIdx.x * 256 + threadIdx.x;
  if (id >= NB * 64 * HW) return;
  int b = id / (64*HW), id2 = id - b*(64*HW);
  int co = id2 / HW, p = id2 - co * HW;
  int y = p / 48, xx = p - y * 48;
  float acc = 0.f;
  #pragma unroll
  for (int dy = -1; dy <= 1; dy++){
    int yy = y + dy; if (yy < 0 || yy >= 48) continue;
    #pragma unroll
    for (int dx = -1; dx <= 1; dx++){
      int x2 = xx + dx; if (x2 < 0 || x2 >= 48) continue;
      acc += __half2float(T[((size_t)b*HW + yy*48 + x2) * 576 + co*9 + (1-dy)*3 + (1-dx)]);
    }
  }
  size_t gi = (size_t)id;
  float r = x[gi] + 0.25f * acc;
  if (flag[0]) ((__hip_bfloat16*)out)[gi] = __float2bfloat16(r);
  else         ((float*)out)[gi] = r;
}

extern "C" void kernel_launch(void* const* d_in, const int* in_sizes, int n_in,
                              void* d_out, int out_size, void* d_ws, size_t ws_size,
                              hipStream_t stream){
  (void)out_size; (void)n_in;

  char* cur = (char*)d_ws;
  auto carve = [&](size_t bytes)->char*{
    char* p = cur; cur += (bytes + 255) & ~(size_t)255; return p;
  };
  int*   flag  = (int*)  carve(4);
  float* canon[10];
  for (int i = 0; i < 10; i++) canon[i] = (float*)carve((size_t)in_sizes[i] * 4);
  float* xc = canon[0];
  float* Wb = canon[1]; float* bb = canon[2]; float* ab = canon[3];
  float* Wm = canon[4]; float* bm = canon[5]; float* am = canon[6];
  float* Wa = canon[7]; float* ba = canon[8]; float* aa = canon[9];

  h16*   xs    = (h16*)  carve((size_t)NB * 64 * NP * 2);
  float* mbuf  = (float*)carve((size_t)NB * 32 * HW * 4);
  float* mat   = (float*)carve((size_t)NB * 32 * NP * 4);
  float* ninv  = (float*)carve((size_t)NB * NP * 4);
  h16*   baseh = (h16*)  carve((size_t)NB * 64 * NP * 2);
  h16*   U     = (h16*)  carve((size_t)NB * HW * 288 * 2);
  h16*   RpT   = (h16*)  carve((size_t)NB * NT * 576 * 32 * 2);
  h16*   T     = (h16*)  carve((size_t)NB * HW * 576 * 2);

  size_t fixed = (size_t)(cur - (char*)d_ws);
  size_t perb  = (((size_t)NPAD*288*2 + 255) & ~(size_t)255)
               + (((size_t)HW*SW2*2 + 255) & ~(size_t)255)
               + 3 * (((size_t)NBLK*HW*4 + 255) & ~(size_t)255);
  size_t avail = (ws_size > fixed) ? ws_size - fixed : 0;
  int g = (int)(avail / perb);
  if (g < 1) g = 1;
  if (g > NB) g = NB;
  h16*   Wp  = (h16*)  carve((size_t)g * NPAD * 288 * 2);
  h16*   S16 = (h16*)  carve((size_t)g * HW * SW2 * 2);
  float* Pm  = (float*)carve((size_t)g * NBLK * HW * 4);
  float* Ps  = (float*)carve((size_t)g * NBLK * HW * 4);
  float* Fac = (float*)carve((size_t)g * NBLK * HW * 4);

  k_detect<<<1, 256, 0, stream>>>(d_in[0], flag);
  {
    CanonArgs ca; int tot = 0;
    for (int i = 0; i < 10; i++){
      ca.src[i] = d_in[i]; ca.dst[i] = canon[i];
      tot += in_sizes[i]; ca.end[i] = tot;
    }
    k_canon_all<<<(tot + 255)/256, 256, 0, stream>>>(ca, tot, flag);
  }

  k_resize<<<(NB*NP + 255)/256, 256, 0, stream>>>(xc, xs);

  dim3 gm((NP + 63)/64, NB);
  k_conv1x1<false><<<gm, 256, 0, stream>>>(xs, Wm, bm, am, (void*)mat,   NP, 32, (size_t)64*NP, (size_t)32*NP, NP, NP);
  k_conv1x1<true ><<<gm, 256, 0, stream>>>(xs, Wa, ba, aa, (void*)baseh, NP, 64, (size_t)64*NP, (size_t)64*NP, NP, NP);
  dim3 gb2((HW + 63)/64, NB);
  k_conv1x1<false><<<gb2, 256, 0, stream>>>(xs, Wb, bb, ab, (void*)mbuf, HW, 32, (size_t)64*NP, (size_t)32*HW, NP, HW);

  k_norminv<<<(NB*NP + 255)/256, 256, 0, stream>>>(mat, ninv);
  k_packU<<<((size_t)NB*HW*288 + 255)/256, 256, 0, stream>>>(mbuf, U);
  k_packR<<<((size_t)NB*NT*576*32 + 255)/256, 256, 0, stream>>>(baseh, RpT);

  for (int b0 = 0; b0 < NB; b0 += g){
    int gc = (b0 + g <= NB) ? g : (NB - b0);
    k_packW<<<((size_t)gc*NPAD*288 + 255)/256, 256, 0, stream>>>(mat, ninv, Wp, b0, gc);
    dim3 g1(NBLK, HW/128, gc);
    k_gemm1m<<<g1, 512, 0, stream>>>((const f16*)U, (const f16*)Wp, S16, Pm, Ps, b0);
    k_sfac<<<(gc*HW + 255)/256, 256, 0, stream>>>(Pm, Ps, Fac, gc);
    dim3 g2(3, HW/128, gc);
    k_gemm2n<<<g2, 384, 0, stream>>>(S16, RpT, Fac, T, b0);
  }

  k_fold<<<(NB*64*HW + 255)/256, 256, 0, stream>>>(T, xc, d_out, flag);
}

// Round 6
// 519.605 us; speedup vs baseline: 6.9471x; 1.1564x over previous
//
#include <hip/hip_runtime.h>
#include <hip/hip_bf16.h>
#include <hip/hip_fp16.h>

typedef __half h16;
typedef _Float16 f16;
typedef f16 f16x8 __attribute__((ext_vector_type(8)));
typedef __attribute__((ext_vector_type(4))) float f32x4;

#define NB 4
#define NCH 64
#define HW 2304      // 48*48
#define NP 7470      // total patches across 5 scales
#define NPAD 7552    // 59*128 = 236*32
#define NT 236       // k-tiles of 32
#define NBLK 59      // 128-col blocks
#define SW2 NPAD

__device__ __forceinline__ float us2f(unsigned short u){
  unsigned v = (unsigned)u << 16; float f; __builtin_memcpy(&f, &v, 4); return f;
}
__device__ __forceinline__ void gl16(const void* g, void* l){
  __builtin_amdgcn_global_load_lds((const __attribute__((address_space(1))) unsigned int*)g,
                                   (__attribute__((address_space(3))) unsigned int*)l, 16, 0, 0);
}

// n -> (scale offset, dim, y, x). dims 48,43,38,33,28; offsets 0,2304,4153,5597,6686
__device__ __forceinline__ void n_decode(int n, int& off, int& d, int& y, int& x){
  if (n < 2304)      { off = 0;    d = 48; }
  else if (n < 4153) { off = 2304; d = 43; }
  else if (n < 5597) { off = 4153; d = 38; }
  else if (n < 6686) { off = 5597; d = 33; }
  else               { off = 6686; d = 28; }
  int l = n - off; y = l / d; x = l - y * d;
}

// ---- dtype probe (proven R3-R5) ----
__global__ __launch_bounds__(256) void k_detect(const void* __restrict__ x, int* __restrict__ flag){
  const unsigned short* u = (const unsigned short*)x;
  int tid = threadIdx.x;
  int c = 0;
  for (int i = tid; i < 8192; i += 256){
    float v = us2f(u[i]);
    float a = fabsf(v);
    if (v == 0.f || (a > 1e-5f && a < 1e3f)) c++;
  }
  #pragma unroll
  for (int o = 1; o < 64; o <<= 1) c += __shfl_xor(c, o);
  __shared__ int wr[4];
  if ((tid & 63) == 0) wr[tid >> 6] = c;
  __syncthreads();
  if (tid == 0) flag[0] = ((wr[0]+wr[1]+wr[2]+wr[3]) > 7000) ? 1 : 0;
}

struct CanonArgs { const void* src[10]; float* dst[10]; int end[10]; };

__global__ __launch_bounds__(256) void k_canon_all(CanonArgs a, int tot, const int* __restrict__ flag){
  int id = blockIdx.x * 256 + threadIdx.x;
  if (id >= tot) return;
  int k = 0;
  while (id >= a.end[k]) k++;
  int local = id - (k ? a.end[k-1] : 0);
  float v;
  if (flag[0]) v = us2f(((const unsigned short*)a.src[k])[local]);
  else         v = ((const float*)a.src[k])[local];
  a.dst[k][local] = v;
}

// Bilinear resize (half-pixel, antialias=False): x fp32 -> xs f16 [b][c][n]
__global__ __launch_bounds__(256) void k_resize(const float* __restrict__ x, h16* __restrict__ xs){
  int id = blockIdx.x * 256 + threadIdx.x;
  if (id >= NB * NP) return;
  int b = id / NP, n = id - b * NP;
  int off, d, y, xx; n_decode(n, off, d, y, xx);
  const float* xb = x + (size_t)b * NCH * HW;
  h16* o = xs + (size_t)b * NCH * NP + n;
  if (off == 0){
    int p = y * 48 + xx;
    for (int c = 0; c < NCH; c++) o[(size_t)c * NP] = __float2half(xb[c * HW + p]);
  } else {
    float cy = (y + 0.5f) * (48.0f / (float)d) - 0.5f;
    float cx = (xx + 0.5f) * (48.0f / (float)d) - 0.5f;
    int y0 = (int)floorf(cy), x0 = (int)floorf(cx);
    float fy = cy - (float)y0, fx = cx - (float)x0;
    int y1 = min(y0 + 1, 47), x1 = min(x0 + 1, 47);
    y0 = max(y0, 0); x0 = max(x0, 0);
    float w00 = (1.f-fy)*(1.f-fx), w01 = (1.f-fy)*fx, w10 = fy*(1.f-fx), w11 = fy*fx;
    for (int c = 0; c < NCH; c++){
      const float* pc = xb + c * HW;
      float v = w00 * pc[y0*48+x0] + w01 * pc[y0*48+x1]
              + w10 * pc[y1*48+x0] + w11 * pc[y1*48+x1];
      o[(size_t)c * NP] = __float2half(v);
    }
  }
}

// 1x1 conv (Cin=64) + PReLU; in f16 [64][rs_in]; out fp32 or f16.
template<bool OB>
__global__ __launch_bounds__(256) void k_conv1x1(const h16* __restrict__ in, const float* __restrict__ Wt,
    const float* __restrict__ bias, const float* __restrict__ alpha, void* __restrict__ outv,
    int npix, int cout, size_t in_bstride, size_t out_bstride, int rs_in, int rs_out){
  __shared__ float Wl[64*64];
  __shared__ float it[64][64];
  int b = blockIdx.y;
  int n0 = blockIdx.x * 64;
  int tid = threadIdx.x;
  const h16* ib = in + (size_t)b * in_bstride;
  for (int i = tid; i < cout * 64; i += 256) Wl[i] = Wt[i];
  for (int i = tid; i < 64 * 64; i += 256){
    int ci = i >> 6, nn = i & 63;
    int n = n0 + nn;
    it[ci][nn] = (n < npix) ? __half2float(ib[(size_t)ci * rs_in + n]) : 0.f;
  }
  __syncthreads();
  float al = alpha[0];
  for (int oi = tid; oi < cout * 64; oi += 256){
    int co = oi >> 6, nn = oi & 63;
    float acc = bias[co];
    #pragma unroll
    for (int ci = 0; ci < 64; ci++) acc = fmaf(Wl[co*64+ci], it[ci][nn], acc);
    acc = acc >= 0.f ? acc : al * acc;
    int n = n0 + nn;
    if (n < npix){
      size_t idx = (size_t)b * out_bstride + (size_t)co * rs_out + n;
      if constexpr (OB) ((h16*)outv)[idx] = __float2half(acc);
      else              ((float*)outv)[idx] = acc;
    }
  }
}

// 1/max(||mat patch||,1e-4) per (b,n)
__global__ __launch_bounds__(256) void k_norminv(const float* __restrict__ mat, float* __restrict__ ninv){
  int id = blockIdx.x * 256 + threadIdx.x;
  if (id >= NB * NP) return;
  int b = id / NP, n = id - b * NP;
  int off, d, y, x; n_decode(n, off, d, y, x);
  const float* mp = mat + (size_t)b * 32 * NP + off;
  float s = 0.f;
  for (int c = 0; c < 32; c++){
    const float* pc = mp + (size_t)c * NP;
    #pragma unroll
    for (int dy = -1; dy <= 1; dy++){
      int yy = y + dy; if (yy < 0 || yy >= d) continue;
      #pragma unroll
      for (int dx = -1; dx <= 1; dx++){
        int xx = x + dx; if (xx < 0 || xx >= d) continue;
        float v = pc[yy * d + xx]; s += v * v;
      }
    }
  }
  ninv[id] = 1.f / fmaxf(sqrtf(s), 1e-4f);
}

// unfold match_base -> U[b][2304][288] f16
__global__ __launch_bounds__(256) void k_packU(const float* __restrict__ mb, h16* __restrict__ U){
  int id = blockIdx.x * 256 + threadIdx.x;
  if (id >= NB * HW * 288) return;
  int b = id / (HW*288), rem = id - b*(HW*288);
  int p = rem / 288, k = rem - p * 288;
  int c = k / 9, r = k - c * 9, kh = r / 3, kw = r - kh * 3;
  int y = p / 48 + kh - 1, x = (p % 48) + kw - 1;
  float v = 0.f;
  if (y >= 0 && y < 48 && x >= 0 && x < 48)
    v = mb[((size_t)b * 32 + c) * HW + y * 48 + x];
  U[id] = __float2half(v);
}

// unfold mat * (10*ninv) -> Wp[g][NPAD][288] f16
__global__ __launch_bounds__(256) void k_packW(const float* __restrict__ mat, const float* __restrict__ ninv,
                                               h16* __restrict__ Wp, int b0, int g){
  int id = blockIdx.x * 256 + threadIdx.x;
  if (id >= g * NPAD * 288) return;
  int bg = id / (NPAD*288), rem = id - bg*(NPAD*288);
  int n = rem / 288, k = rem - n * 288;
  float v = 0.f;
  if (n < NP){
    int b = b0 + bg;
    int c = k / 9, r = k - c * 9, kh = r / 3, kw = r - kh * 3;
    int off, d, y, x; n_decode(n, off, d, y, x);
    int yy = y + kh - 1, xx = x + kw - 1;
    if (yy >= 0 && yy < d && xx >= 0 && xx < d)
      v = mat[((size_t)b * 32 + c) * NP + off + yy * d + xx] * 10.f * ninv[(size_t)b*NP + n];
  }
  Wp[id] = __float2half(v);
}

// unfold base (f16) -> RpT[b][t][576][32] f16
__global__ __launch_bounds__(256) void k_packR(const h16* __restrict__ src, h16* __restrict__ dst){
  int id = blockIdx.x * 256 + threadIdx.x;
  if (id >= NB * NT * 576 * 32) return;
  int b = id / (NT*576*32), rem = id - b*(NT*576*32);
  int t = rem / (576*32), rem2 = rem - t*(576*32);
  int j = rem2 / 32, kl = rem2 - j*32;
  int n = t*32 + kl;
  h16 v = __float2half(0.f);
  if (n < NP){
    int c = j / 9, r = j - c * 9, kh = r / 3, kw = r - kh * 3;
    int off, d, y, x; n_decode(n, off, d, y, x);
    int yy = y + kh - 1, xx = x + kw - 1;
    if (yy >= 0 && yy < d && xx >= 0 && xx < d)
      v = src[((size_t)b * 64 + c) * NP + off + yy * d + xx];
  }
  dst[id] = v;
}

// GEMM1 + fused block-local softmax stats; 2-phase prefetch, 2-way swizzle.
// S16[bg][m][n] = exp(s - Mloc) fp16 (pad->0); Pm/Ps[bg][nblk][m] = Mloc, sum.
__global__ __launch_bounds__(512) void k_gemm1m(const f16* __restrict__ U, const f16* __restrict__ Wp,
    h16* __restrict__ S16, float* __restrict__ Pm, float* __restrict__ Ps, int b0){
  int bg = blockIdx.z, b = b0 + bg;
  int m0 = blockIdx.y * 128, n0 = blockIdx.x * 128;
  int tid = threadIdx.x, l = tid & 63, w = tid >> 6;
  int wm = w >> 1, wn = w & 1;
  int ch = l >> 4, cl = l & 15;
  __shared__ __align__(16) char At[2][8192];
  __shared__ __align__(16) char Bt[2][8192];
  __shared__ float mred[128][2];
  __shared__ float sred[128][2];
  f32x4 acc[2][4] = {};
  const f16* Ub = U + ((size_t)b * HW + m0) * 288;
  const f16* Wb = Wp + ((size_t)bg * NPAD + n0) * 288;
  int abyte[2], bbyte[4];
  #pragma unroll
  for (int mt = 0; mt < 2; mt++){
    int lr = wm*32 + mt*16 + cl;
    abyte[mt] = lr*64 + ((ch ^ ((lr>>1)&3))<<4);
  }
  #pragma unroll
  for (int nt = 0; nt < 4; nt++){
    int lr = wn*64 + nt*16 + cl;
    bbyte[nt] = lr*64 + ((ch ^ ((lr>>1)&3))<<4);
  }
  int srow = tid >> 2, scs = (tid & 3) ^ ((srow >> 1) & 3);
  // prologue stage
  gl16(Ub + (size_t)srow*288 + 0 + scs*8, At[0] + tid*16);
  gl16(Wb + (size_t)srow*288 + 0 + scs*8, Bt[0] + tid*16);
  __syncthreads();
  int cur = 0;
  for (int k0 = 0; k0 < 288; k0 += 32){
    if (k0 + 32 < 288){
      gl16(Ub + (size_t)srow*288 + k0 + 32 + scs*8, At[cur^1] + tid*16);
      gl16(Wb + (size_t)srow*288 + k0 + 32 + scs*8, Bt[cur^1] + tid*16);
    }
    f16x8 a[2], bv[4];
    #pragma unroll
    for (int mt = 0; mt < 2; mt++) a[mt] = *reinterpret_cast<const f16x8*>(At[cur] + abyte[mt]);
    #pragma unroll
    for (int nt = 0; nt < 4; nt++) bv[nt] = *reinterpret_cast<const f16x8*>(Bt[cur] + bbyte[nt]);
    #pragma unroll
    for (int mt = 0; mt < 2; mt++)
      #pragma unroll
      for (int nt = 0; nt < 4; nt++)
        acc[mt][nt] = __builtin_amdgcn_mfma_f32_16x16x32_f16(a[mt], bv[nt], acc[mt][nt], 0, 0, 0);
    __syncthreads();
    cur ^= 1;
  }
  // block-local row max over 128 cols
  #pragma unroll
  for (int mt = 0; mt < 2; mt++)
    #pragma unroll
    for (int i = 0; i < 4; i++){
      float v = -3e38f;
      #pragma unroll
      for (int nt = 0; nt < 4; nt++){
        int gn = n0 + wn*64 + nt*16 + cl;
        float t = acc[mt][nt][i];
        v = fmaxf(v, (gn < NP) ? t : -3e38f);
      }
      v = fmaxf(v, __shfl_xor(v, 1));
      v = fmaxf(v, __shfl_xor(v, 2));
      v = fmaxf(v, __shfl_xor(v, 4));
      v = fmaxf(v, __shfl_xor(v, 8));
      if (cl == 0) mred[wm*32 + mt*16 + ch*4 + i][wn] = v;
    }
  __syncthreads();
  // exp, write S16, row sums
  #pragma unroll
  for (int mt = 0; mt < 2; mt++)
    #pragma unroll
    for (int i = 0; i < 4; i++){
      int r = wm*32 + mt*16 + ch*4 + i;
      float Ml = fmaxf(mred[r][0], mred[r][1]);
      int gm = m0 + r;
      float s = 0.f;
      #pragma unroll
      for (int nt = 0; nt < 4; nt++){
        int gn = n0 + wn*64 + nt*16 + cl;
        float e = (gn < NP) ? __expf(acc[mt][nt][i] - Ml) : 0.f;
        S16[((size_t)bg*HW + gm)*SW2 + gn] = __float2half(e);
        s += e;
      }
      s += __shfl_xor(s, 1);
      s += __shfl_xor(s, 2);
      s += __shfl_xor(s, 4);
      s += __shfl_xor(s, 8);
      if (cl == 0) sred[r][wn] = s;
    }
  __syncthreads();
  if (tid < 128){
    float Mf = fmaxf(mred[tid][0], mred[tid][1]);
    float L  = sred[tid][0] + sred[tid][1];
    size_t o = ((size_t)bg*NBLK + blockIdx.x)*HW + m0 + tid;
    Pm[o] = Mf; Ps[o] = L;
  }
}

// combine partials: Fac[bg][nblk][row] = exp(Mloc - Mglob) / L_glob
__global__ __launch_bounds__(256) void k_sfac(const float* __restrict__ Pm, const float* __restrict__ Ps,
                                              float* __restrict__ Fac, int gc){
  int id = blockIdx.x * 256 + threadIdx.x;
  if (id >= gc * HW) return;
  int bg = id / HW, r = id - bg * HW;
  const float* pm = Pm + (size_t)bg*NBLK*HW + r;
  const float* ps = Ps + (size_t)bg*NBLK*HW + r;
  float M = -3e38f;
  for (int k = 0; k < NBLK; k++) M = fmaxf(M, pm[(size_t)k*HW]);
  float L = 0.f;
  for (int k = 0; k < NBLK; k++) L += __expf(pm[(size_t)k*HW] - M) * ps[(size_t)k*HW];
  float inv = 1.f / L;
  float* fo = Fac + (size_t)bg*NBLK*HW + r;
  for (int k = 0; k < NBLK; k++) fo[(size_t)k*HW] = __expf(pm[(size_t)k*HW] - M) * inv;
}

// GEMM2: T[b][m][j] = sum_k (S16[m][k]*Fac) * RpT[k][j]
// BM=64, BN=192, BK=32; 384 thr (6 waves = 2 wm x 3 wc), dbuf prefetch,
// XCD-chunked block swizzle so the 3 jh blocks sharing S-rows colocate.
__global__ __launch_bounds__(384) void k_gemm2n(const f16* __restrict__ S16, const f16* __restrict__ RpT,
    const float* __restrict__ Fac, h16* __restrict__ T, int b0){
  int nwg = gridDim.x;
  int p = blockIdx.x;
  int L = (nwg % 8 == 0) ? ((p & 7)*(nwg>>3) + (p>>3)) : p;
  int jh = L % 3; int t1 = L / 3; int my = t1 % 36; int bg = t1 / 36;
  int b = b0 + bg;
  int m0 = my * 64;
  int tid = threadIdx.x, l = tid & 63, w = tid >> 6;
  int wm = w / 3, wc = w % 3;
  int ch = l >> 4, cl = l & 15;
  __shared__ __align__(16) char Ss[2][4096];    // [64][32] f16, 2-way swizzle
  __shared__ __align__(16) char Rt[2][12288];   // [192][32] f16
  __shared__ float fl[NBLK*64];                 // fac slice for this m-block
  f32x4 acc[2][4] = {};
  int abyte[2], rbyte[4], lrow[2];
  #pragma unroll
  for (int mt = 0; mt < 2; mt++){
    int lr = wm*32 + mt*16 + cl;
    lrow[mt] = lr;
    abyte[mt] = lr*64 + ((ch ^ ((lr>>1)&3))<<4);
  }
  #pragma unroll
  for (int nt = 0; nt < 4; nt++){
    int jr = wc*64 + nt*16 + cl;
    rbyte[nt] = jr*64 + ((ch ^ ((jr>>1)&3))<<4);
  }
  const f16* Sb  = S16 + ((size_t)bg*HW + m0)*SW2;
  const f16* Rb0 = RpT + (size_t)b*((size_t)NT*576*32) + (size_t)jh*(192*32);
  const float* facb = Fac + (size_t)bg*NBLK*HW + m0;
  int srow = tid >> 2, scs = (tid & 3) ^ ((srow >> 1) & 3);
  int r2 = (tid + 384) >> 2, c2 = ((tid + 384) & 3) ^ ((r2 >> 1) & 3);
  // preload fac slice
  for (int i = tid; i < NBLK*64; i += 384)
    fl[i] = facb[(size_t)(i >> 6)*HW + (i & 63)];
  // prologue stage tile 0
  {
    if (tid < 256) gl16(Sb + (size_t)srow*SW2 + scs*8, Ss[0] + tid*16);
    const f16* Rb = Rb0;
    gl16(Rb + (size_t)srow*32 + scs*8, Rt[0] + tid*16);
    gl16(Rb + (size_t)r2*32 + c2*8, Rt[0] + (tid+384)*16);
  }
  __syncthreads();
  int cur = 0;
  for (int t = 0; t < NT; ++t){
    if (t + 1 < NT){
      if (tid < 256) gl16(Sb + (size_t)srow*SW2 + (t+1)*32 + scs*8, Ss[cur^1] + tid*16);
      const f16* Rb = Rb0 + (size_t)(t+1)*(576*32);
      gl16(Rb + (size_t)srow*32 + scs*8, Rt[cur^1] + tid*16);
      gl16(Rb + (size_t)r2*32 + c2*8, Rt[cur^1] + (tid+384)*16);
    }
    int nb = t >> 2;
    f16 fac0 = (f16)fl[nb*64 + lrow[0]];
    f16 fac1 = (f16)fl[nb*64 + lrow[1]];
    f16x8 pa[2], bv[4];
    {
      f16x8 s0 = *reinterpret_cast<const f16x8*>(Ss[cur] + abyte[0]);
      f16x8 s1 = *reinterpret_cast<const f16x8*>(Ss[cur] + abyte[1]);
      pa[0] = s0 * fac0;
      pa[1] = s1 * fac1;
    }
    #pragma unroll
    for (int nt = 0; nt < 4; nt++) bv[nt] = *reinterpret_cast<const f16x8*>(Rt[cur] + rbyte[nt]);
    #pragma unroll
    for (int mt = 0; mt < 2; mt++)
      #pragma unroll
      for (int nt = 0; nt < 4; nt++)
        acc[mt][nt] = __builtin_amdgcn_mfma_f32_16x16x32_f16(pa[mt], bv[nt], acc[mt][nt], 0, 0, 0);
    __syncthreads();
    cur ^= 1;
  }
  #pragma unroll
  for (int mt = 0; mt < 2; mt++)
    #pragma unroll
    for (int nt = 0; nt < 4; nt++)
      #pragma unroll
      for (int i = 0; i < 4; i++){
        int gm = m0 + wm*32 + mt*16 + ch*4 + i;
        int gc = jh*192 + wc*64 + nt*16 + cl;
        T[((size_t)b*HW + gm)*576 + gc] = __float2half(acc[mt][nt][i]);
      }
}

// out[b,co,y,x] = x + 0.25 * fold(T); output dtype per flag (0=f32, 1=bf16)
__global__ __launch_bounds__(256) void k_fold(const h16* __restrict__ T, const float* __restrict__ x,
    void* __restrict__ out, const int* __restrict__ flag){
  int id = blockIdx.x * 256 + threadIdx.x;
  if (id >= NB * 64 * HW) return;
  int b = id / (64*HW), id2 = id - b*(64*HW);
  int co = id2 / HW, p = id2 - co * HW;
  int y = p / 48, xx = p - y * 48;
  float acc = 0.f;
  #pragma unroll
  for (int dy = -1; dy <= 1; dy++){
    int yy = y + dy; if (yy < 0 || yy >= 48) continue;
    #pragma unroll
    for (int dx = -1; dx <= 1; dx++){
      int x2 = xx + dx; if (x2 < 0 || x2 >= 48) continue;
      acc += __half2float(T[((size_t)b*HW + yy*48 + x2) * 576 + co*9 + (1-dy)*3 + (1-dx)]);
    }
  }
  size_t gi = (size_t)id;
  float r = x[gi] + 0.25f * acc;
  if (flag[0]) ((__hip_bfloat16*)out)[gi] = __float2bfloat16(r);
  else         ((float*)out)[gi] = r;
}

extern "C" void kernel_launch(void* const* d_in, const int* in_sizes, int n_in,
                              void* d_out, int out_size, void* d_ws, size_t ws_size,
                              hipStream_t stream){
  (void)out_size; (void)n_in;

  char* cur = (char*)d_ws;
  auto carve = [&](size_t bytes)->char*{
    char* p = cur; cur += (bytes + 255) & ~(size_t)255; return p;
  };
  int*   flag  = (int*)  carve(4);
  float* canon[10];
  for (int i = 0; i < 10; i++) canon[i] = (float*)carve((size_t)in_sizes[i] * 4);
  float* xc = canon[0];
  float* Wb = canon[1]; float* bb = canon[2]; float* ab = canon[3];
  float* Wm = canon[4]; float* bm = canon[5]; float* am = canon[6];
  float* Wa = canon[7]; float* ba = canon[8]; float* aa = canon[9];

  h16*   xs    = (h16*)  carve((size_t)NB * 64 * NP * 2);
  float* mbuf  = (float*)carve((size_t)NB * 32 * HW * 4);
  float* mat   = (float*)carve((size_t)NB * 32 * NP * 4);
  float* ninv  = (float*)carve((size_t)NB * NP * 4);
  h16*   baseh = (h16*)  carve((size_t)NB * 64 * NP * 2);
  h16*   U     = (h16*)  carve((size_t)NB * HW * 288 * 2);
  h16*   RpT   = (h16*)  carve((size_t)NB * NT * 576 * 32 * 2);
  h16*   T     = (h16*)  carve((size_t)NB * HW * 576 * 2);

  size_t fixed = (size_t)(cur - (char*)d_ws);
  size_t perb  = (((size_t)NPAD*288*2 + 255) & ~(size_t)255)
               + (((size_t)HW*SW2*2 + 255) & ~(size_t)255)
               + 3 * (((size_t)NBLK*HW*4 + 255) & ~(size_t)255);
  size_t avail = (ws_size > fixed) ? ws_size - fixed : 0;
  int g = (int)(avail / perb);
  if (g < 1) g = 1;
  if (g > NB) g = NB;
  h16*   Wp  = (h16*)  carve((size_t)g * NPAD * 288 * 2);
  h16*   S16 = (h16*)  carve((size_t)g * HW * SW2 * 2);
  float* Pm  = (float*)carve((size_t)g * NBLK * HW * 4);
  float* Ps  = (float*)carve((size_t)g * NBLK * HW * 4);
  float* Fac = (float*)carve((size_t)g * NBLK * HW * 4);

  k_detect<<<1, 256, 0, stream>>>(d_in[0], flag);
  {
    CanonArgs ca; int tot = 0;
    for (int i = 0; i < 10; i++){
      ca.src[i] = d_in[i]; ca.dst[i] = canon[i];
      tot += in_sizes[i]; ca.end[i] = tot;
    }
    k_canon_all<<<(tot + 255)/256, 256, 0, stream>>>(ca, tot, flag);
  }

  k_resize<<<(NB*NP + 255)/256, 256, 0, stream>>>(xc, xs);

  dim3 gm((NP + 63)/64, NB);
  k_conv1x1<false><<<gm, 256, 0, stream>>>(xs, Wm, bm, am, (void*)mat,   NP, 32, (size_t)64*NP, (size_t)32*NP, NP, NP);
  k_conv1x1<true ><<<gm, 256, 0, stream>>>(xs, Wa, ba, aa, (void*)baseh, NP, 64, (size_t)64*NP, (size_t)64*NP, NP, NP);
  dim3 gb2((HW + 63)/64, NB);
  k_conv1x1<false><<<gb2, 256, 0, stream>>>(xs, Wb, bb, ab, (void*)mbuf, HW, 32, (size_t)64*NP, (size_t)32*HW, NP, HW);

  k_norminv<<<(NB*NP + 255)/256, 256, 0, stream>>>(mat, ninv);
  k_packU<<<((size_t)NB*HW*288 + 255)/256, 256, 0, stream>>>(mbuf, U);
  k_packR<<<((size_t)NB*NT*576*32 + 255)/256, 256, 0, stream>>>(baseh, RpT);

  for (int b0 = 0; b0 < NB; b0 += g){
    int gc = (b0 + g <= NB) ? g : (NB - b0);
    k_packW<<<((size_t)gc*NPAD*288 + 255)/256, 256, 0, stream>>>(mat, ninv, Wp, b0, gc);
    dim3 g1(NBLK, HW/128, gc);
    k_gemm1m<<<g1, 512, 0, stream>>>((const f16*)U, (const f16*)Wp, S16, Pm, Ps, b0);
    k_sfac<<<(gc*HW + 255)/256, 256, 0, stream>>>(Pm, Ps, Fac, gc);
    int nwg2 = 3 * 36 * gc;
    k_gemm2n<<<nwg2, 384, 0, stream>>>((const f16*)S16, (const f16*)RpT, Fac, T, b0);
  }

  k_fold<<<(NB*64*HW + 255)/256, 256, 0, stream>>>(T, xc, d_out, flag);
}

// Round 9
// 468.599 us; speedup vs baseline: 7.7033x; 1.1088x over previous
//
#include <hip/hip_runtime.h>
#include <hip/hip_bf16.h>
#include <hip/hip_fp16.h>

typedef __half h16;
typedef _Float16 f16;
typedef f16 f16x8 __attribute__((ext_vector_type(8)));
typedef __attribute__((ext_vector_type(4))) float f32x4;

#define NB 4
#define NCH 64
#define HW 2304      // 48*48
#define NP 7470      // total patches across 5 scales
#define NPAD 7552    // 59*128 = 236*32
#define NT 236       // k-tiles of 32
#define NBLK 59      // 128-col blocks
#define SW2 NPAD

__device__ __forceinline__ float us2f(unsigned short u){
  unsigned v = (unsigned)u << 16; float f; __builtin_memcpy(&f, &v, 4); return f;
}
__device__ __forceinline__ void gl16(const void* g, void* l){
  __builtin_amdgcn_global_load_lds((const __attribute__((address_space(1))) unsigned int*)g,
                                   (__attribute__((address_space(3))) unsigned int*)l, 16, 0, 0);
}

// n -> (scale offset, dim, y, x). dims 48,43,38,33,28; offsets 0,2304,4153,5597,6686
__device__ __forceinline__ void n_decode(int n, int& off, int& d, int& y, int& x){
  if (n < 2304)      { off = 0;    d = 48; }
  else if (n < 4153) { off = 2304; d = 43; }
  else if (n < 5597) { off = 4153; d = 38; }
  else if (n < 6686) { off = 5597; d = 33; }
  else               { off = 6686; d = 28; }
  int l = n - off; y = l / d; x = l - y * d;
}

// ---- dtype probe (proven R3-R6) ----
__global__ __launch_bounds__(256) void k_detect(const void* __restrict__ x, int* __restrict__ flag){
  const unsigned short* u = (const unsigned short*)x;
  int tid = threadIdx.x;
  int c = 0;
  for (int i = tid; i < 8192; i += 256){
    float v = us2f(u[i]);
    float a = fabsf(v);
    if (v == 0.f || (a > 1e-5f && a < 1e3f)) c++;
  }
  #pragma unroll
  for (int o = 1; o < 64; o <<= 1) c += __shfl_xor(c, o);
  __shared__ int wr[4];
  if ((tid & 63) == 0) wr[tid >> 6] = c;
  __syncthreads();
  if (tid == 0) flag[0] = ((wr[0]+wr[1]+wr[2]+wr[3]) > 7000) ? 1 : 0;
}

struct CanonArgs { const void* src[10]; float* dst[10]; int end[10]; };

__global__ __launch_bounds__(256) void k_canon_all(CanonArgs a, int tot, const int* __restrict__ flag){
  int id = blockIdx.x * 256 + threadIdx.x;
  if (id >= tot) return;
  int k = 0;
  while (id >= a.end[k]) k++;
  int local = id - (k ? a.end[k-1] : 0);
  float v;
  if (flag[0]) v = us2f(((const unsigned short*)a.src[k])[local]);
  else         v = ((const float*)a.src[k])[local];
  a.dst[k][local] = v;
}

// Bilinear resize: thread per output element (b,c,n); coalesced writes.
__global__ __launch_bounds__(256) void k_resize(const float* __restrict__ x, h16* __restrict__ xs){
  int id = blockIdx.x * 256 + threadIdx.x;
  if (id >= NB * NCH * NP) return;
  int b = id / (NCH*NP), rem = id - b*(NCH*NP);
  int c = rem / NP, n = rem - c*NP;
  int off, d, y, xx; n_decode(n, off, d, y, xx);
  const float* pc = x + ((size_t)b * NCH + c) * HW;
  float v;
  if (off == 0){
    v = pc[y*48 + xx];
  } else {
    float cy = (y + 0.5f) * (48.0f / (float)d) - 0.5f;
    float cx = (xx + 0.5f) * (48.0f / (float)d) - 0.5f;
    int y0 = (int)floorf(cy), x0 = (int)floorf(cx);
    float fy = cy - (float)y0, fx = cx - (float)x0;
    int y1 = min(y0 + 1, 47), x1 = min(x0 + 1, 47);
    y0 = max(y0, 0); x0 = max(x0, 0);
    v = (1.f-fy)*((1.f-fx)*pc[y0*48+x0] + fx*pc[y0*48+x1])
      + fy*((1.f-fx)*pc[y1*48+x0] + fx*pc[y1*48+x1]);
  }
  xs[id] = __float2half(v);
}

// 1x1 conv (Cin=64) + PReLU; in f16 [64][rs_in]; out fp32 or f16.
template<bool OB>
__global__ __launch_bounds__(256) void k_conv1x1(const h16* __restrict__ in, const float* __restrict__ Wt,
    const float* __restrict__ bias, const float* __restrict__ alpha, void* __restrict__ outv,
    int npix, int cout, size_t in_bstride, size_t out_bstride, int rs_in, int rs_out){
  __shared__ float Wl[64*64];
  __shared__ float it[64][64];
  int b = blockIdx.y;
  int n0 = blockIdx.x * 64;
  int tid = threadIdx.x;
  const h16* ib = in + (size_t)b * in_bstride;
  for (int i = tid; i < cout * 64; i += 256) Wl[i] = Wt[i];
  for (int i = tid; i < 64 * 64; i += 256){
    int ci = i >> 6, nn = i & 63;
    int n = n0 + nn;
    it[ci][nn] = (n < npix) ? __half2float(ib[(size_t)ci * rs_in + n]) : 0.f;
  }
  __syncthreads();
  float al = alpha[0];
  for (int oi = tid; oi < cout * 64; oi += 256){
    int co = oi >> 6, nn = oi & 63;
    float acc = bias[co];
    #pragma unroll
    for (int ci = 0; ci < 64; ci++) acc = fmaf(Wl[co*64+ci], it[ci][nn], acc);
    acc = acc >= 0.f ? acc : al * acc;
    int n = n0 + nn;
    if (n < npix){
      size_t idx = (size_t)b * out_bstride + (size_t)co * rs_out + n;
      if constexpr (OB) ((h16*)outv)[idx] = __float2half(acc);
      else              ((float*)outv)[idx] = acc;
    }
  }
}

// pass 1: q[b][n] = sum_c mat[c][n]^2 (coalesced over n)
__global__ __launch_bounds__(256) void k_sq(const float* __restrict__ mat, float* __restrict__ q){
  int id = blockIdx.x * 256 + threadIdx.x;
  if (id >= NB * NP) return;
  int b = id / NP, n = id - b * NP;
  const float* mp = mat + (size_t)b * 32 * NP + n;
  float s = 0.f;
  #pragma unroll
  for (int c = 0; c < 32; c++){ float v = mp[(size_t)c * NP]; s += v * v; }
  q[id] = s;
}

// pass 2: ninv[b][n] = 1/max(sqrt(9-tap sum of q), 1e-4)
__global__ __launch_bounds__(256) void k_ninv(const float* __restrict__ q, float* __restrict__ ninv){
  int id = blockIdx.x * 256 + threadIdx.x;
  if (id >= NB * NP) return;
  int b = id / NP, n = id - b * NP;
  int off, d, y, x; n_decode(n, off, d, y, x);
  const float* qb = q + (size_t)b * NP + off;
  float s = 0.f;
  #pragma unroll
  for (int dy = -1; dy <= 1; dy++){
    int yy = y + dy; if (yy < 0 || yy >= d) continue;
    #pragma unroll
    for (int dx = -1; dx <= 1; dx++){
      int xx = x + dx; if (xx < 0 || xx >= d) continue;
      s += qb[yy * d + xx];
    }
  }
  ninv[id] = 1.f / fmaxf(sqrtf(s), 1e-4f);
}

// unfold match_base -> U[b][2304][288] f16
__global__ __launch_bounds__(256) void k_packU(const float* __restrict__ mb, h16* __restrict__ U){
  int id = blockIdx.x * 256 + threadIdx.x;
  if (id >= NB * HW * 288) return;
  int b = id / (HW*288), rem = id - b*(HW*288);
  int p = rem / 288, k = rem - p * 288;
  int c = k / 9, r = k - c * 9, kh = r / 3, kw = r - kh * 3;
  int y = p / 48 + kh - 1, x = (p % 48) + kw - 1;
  float v = 0.f;
  if (y >= 0 && y < 48 && x >= 0 && x < 48)
    v = mb[((size_t)b * 32 + c) * HW + y * 48 + x];
  U[id] = __float2half(v);
}

// unfold mat * (10*ninv) -> Wp[g][NPAD][288] f16
__global__ __launch_bounds__(256) void k_packW(const float* __restrict__ mat, const float* __restrict__ ninv,
                                               h16* __restrict__ Wp, int b0, int g){
  int id = blockIdx.x * 256 + threadIdx.x;
  if (id >= g * NPAD * 288) return;
  int bg = id / (NPAD*288), rem = id - bg*(NPAD*288);
  int n = rem / 288, k = rem - n * 288;
  float v = 0.f;
  if (n < NP){
    int b = b0 + bg;
    int c = k / 9, r = k - c * 9, kh = r / 3, kw = r - kh * 3;
    int off, d, y, x; n_decode(n, off, d, y, x);
    int yy = y + kh - 1, xx = x + kw - 1;
    if (yy >= 0 && yy < d && xx >= 0 && xx < d)
      v = mat[((size_t)b * 32 + c) * NP + off + yy * d + xx] * 10.f * ninv[(size_t)b*NP + n];
  }
  Wp[id] = __float2half(v);
}

// unfold base (f16) -> RpT[b][t][576][32] f16
__global__ __launch_bounds__(256) void k_packR(const h16* __restrict__ src, h16* __restrict__ dst){
  int id = blockIdx.x * 256 + threadIdx.x;
  if (id >= NB * NT * 576 * 32) return;
  int b = id / (NT*576*32), rem = id - b*(NT*576*32);
  int t = rem / (576*32), rem2 = rem - t*(576*32);
  int j = rem2 / 32, kl = rem2 - j*32;
  int n = t*32 + kl;
  h16 v = __float2half(0.f);
  if (n < NP){
    int c = j / 9, r = j - c * 9, kh = r / 3, kw = r - kh * 3;
    int off, d, y, x; n_decode(n, off, d, y, x);
    int yy = y + kh - 1, xx = x + kw - 1;
    if (yy >= 0 && yy < d && xx >= 0 && xx < d)
      v = src[((size_t)b * 64 + c) * NP + off + yy * d + xx];
  }
  dst[id] = v;
}

// GEMM1 + fused block-local softmax stats; dbuf prefetch, 2-way swizzle.
// S16[bg][m][n]=exp(s-Mloc) f16 (pad->0); Pm/Ps layout [bg][m][NBLK].
__global__ __launch_bounds__(512) void k_gemm1m(const f16* __restrict__ U, const f16* __restrict__ Wp,
    h16* __restrict__ S16, float* __restrict__ Pm, float* __restrict__ Ps, int b0){
  int bg = blockIdx.z, b = b0 + bg;
  int m0 = blockIdx.y * 128, n0 = blockIdx.x * 128;
  int tid = threadIdx.x, l = tid & 63, w = tid >> 6;
  int wm = w >> 1, wn = w & 1;
  int ch = l >> 4, cl = l & 15;
  __shared__ __align__(16) char At[2][8192];
  __shared__ __align__(16) char Bt[2][8192];
  __shared__ float mred[128][2];
  __shared__ float sred[128][2];
  f32x4 acc[2][4] = {};
  const f16* Ub = U + ((size_t)b * HW + m0) * 288;
  const f16* Wb = Wp + ((size_t)bg * NPAD + n0) * 288;
  int abyte[2], bbyte[4];
  #pragma unroll
  for (int mt = 0; mt < 2; mt++){
    int lr = wm*32 + mt*16 + cl;
    abyte[mt] = lr*64 + ((ch ^ ((lr>>1)&3))<<4);
  }
  #pragma unroll
  for (int nt = 0; nt < 4; nt++){
    int lr = wn*64 + nt*16 + cl;
    bbyte[nt] = lr*64 + ((ch ^ ((lr>>1)&3))<<4);
  }
  int srow = tid >> 2, scs = (tid & 3) ^ ((srow >> 1) & 3);
  gl16(Ub + (size_t)srow*288 + 0 + scs*8, At[0] + tid*16);
  gl16(Wb + (size_t)srow*288 + 0 + scs*8, Bt[0] + tid*16);
  __syncthreads();
  int cur = 0;
  for (int k0 = 0; k0 < 288; k0 += 32){
    if (k0 + 32 < 288){
      gl16(Ub + (size_t)srow*288 + k0 + 32 + scs*8, At[cur^1] + tid*16);
      gl16(Wb + (size_t)srow*288 + k0 + 32 + scs*8, Bt[cur^1] + tid*16);
    }
    f16x8 a[2], bv[4];
    #pragma unroll
    for (int mt = 0; mt < 2; mt++) a[mt] = *reinterpret_cast<const f16x8*>(At[cur] + abyte[mt]);
    #pragma unroll
    for (int nt = 0; nt < 4; nt++) bv[nt] = *reinterpret_cast<const f16x8*>(Bt[cur] + bbyte[nt]);
    #pragma unroll
    for (int mt = 0; mt < 2; mt++)
      #pragma unroll
      for (int nt = 0; nt < 4; nt++)
        acc[mt][nt] = __builtin_amdgcn_mfma_f32_16x16x32_f16(a[mt], bv[nt], acc[mt][nt], 0, 0, 0);
    __syncthreads();
    cur ^= 1;
  }
  #pragma unroll
  for (int mt = 0; mt < 2; mt++)
    #pragma unroll
    for (int i = 0; i < 4; i++){
      float v = -3e38f;
      #pragma unroll
      for (int nt = 0; nt < 4; nt++){
        int gn = n0 + wn*64 + nt*16 + cl;
        float t = acc[mt][nt][i];
        v = fmaxf(v, (gn < NP) ? t : -3e38f);
      }
      v = fmaxf(v, __shfl_xor(v, 1));
      v = fmaxf(v, __shfl_xor(v, 2));
      v = fmaxf(v, __shfl_xor(v, 4));
      v = fmaxf(v, __shfl_xor(v, 8));
      if (cl == 0) mred[wm*32 + mt*16 + ch*4 + i][wn] = v;
    }
  __syncthreads();
  #pragma unroll
  for (int mt = 0; mt < 2; mt++)
    #pragma unroll
    for (int i = 0; i < 4; i++){
      int r = wm*32 + mt*16 + ch*4 + i;
      float Ml = fmaxf(mred[r][0], mred[r][1]);
      int gm = m0 + r;
      float s = 0.f;
      #pragma unroll
      for (int nt = 0; nt < 4; nt++){
        int gn = n0 + wn*64 + nt*16 + cl;
        float e = (gn < NP) ? __expf(acc[mt][nt][i] - Ml) : 0.f;
        S16[((size_t)bg*HW + gm)*SW2 + gn] = __float2half(e);
        s += e;
      }
      s += __shfl_xor(s, 1);
      s += __shfl_xor(s, 2);
      s += __shfl_xor(s, 4);
      s += __shfl_xor(s, 8);
      if (cl == 0) sred[r][wn] = s;
    }
  __syncthreads();
  if (tid < 128){
    float Mf = fmaxf(mred[tid][0], mred[tid][1]);
    float L  = sred[tid][0] + sred[tid][1];
    size_t o = ((size_t)bg*HW + m0 + tid)*NBLK + blockIdx.x;
    Pm[o] = Mf; Ps[o] = L;
  }
}

// combine partials (wave per row): Fac[bg][m][k] = exp(Mloc-Mglob)/L_glob
__global__ __launch_bounds__(256) void k_sfac(const float* __restrict__ Pm, const float* __restrict__ Ps,
                                              float* __restrict__ Fac, int gc){
  int rid = blockIdx.x * 4 + (threadIdx.x >> 6);
  int lane = threadIdx.x & 63;
  if (rid >= gc * HW) return;
  const float* pm = Pm + (size_t)rid * NBLK;
  const float* ps = Ps + (size_t)rid * NBLK;
  float mv = (lane < NBLK) ? pm[lane] : -3e38f;
  float sv = (lane < NBLK) ? ps[lane] : 0.f;
  float M = mv;
  #pragma unroll
  for (int o = 1; o < 64; o <<= 1) M = fmaxf(M, __shfl_xor(M, o));
  float e = (lane < NBLK) ? __expf(mv - M) : 0.f;
  float c = e * sv;
  #pragma unroll
  for (int o = 1; o < 64; o <<= 1) c += __shfl_xor(c, o);
  float inv = 1.f / c;
  if (lane < NBLK) Fac[(size_t)rid * NBLK + lane] = e * inv;
}

// GEMM2: T[b][j][m] = sum_k (S16[m][k]*Fac) * RpT[k][j]
// BM=32, BN=192; 384 thr (6 waves = 2 wm x 3 wc); dbuf prefetch; XCD swizzle;
// j-major T epilogue staged via LDS for coalesced fold reads.
__global__ __launch_bounds__(384) void k_gemm2n(const f16* __restrict__ S16, const f16* __restrict__ RpT,
    const float* __restrict__ Fac, h16* __restrict__ T, int b0){
  int nwg = gridDim.x;
  int p = blockIdx.x;
  int L = (p & 7) * (nwg >> 3) + (p >> 3);     // nwg % 8 == 0 always (216*gc)
  int jh = L % 3; int t1 = L / 3; int my = t1 % 72; int bg = t1 / 72;
  int b = b0 + bg;
  int m0 = my * 32;
  int tid = threadIdx.x, l = tid & 63, w = tid >> 6;
  int wm = w / 3, wc = w % 3;
  int ch = l >> 4, cl = l & 15;
  __shared__ __align__(16) char smem[33536];
  // layout: Ss0 @0, Ss1 @2048, Rt0 @4096, Rt1 @16384, fl @28672 ([32][64] f16)
  f32x4 acc[4] = {};
  int lr = wm*16 + cl;
  int abyte = lr*64 + ((ch ^ ((lr>>1)&3))<<4);
  int rbyte[4];
  #pragma unroll
  for (int nt = 0; nt < 4; nt++){
    int jr = wc*64 + nt*16 + cl;
    rbyte[nt] = jr*64 + ((ch ^ ((jr>>1)&3))<<4);
  }
  const f16* Sb  = S16 + ((size_t)bg*HW + m0)*SW2;
  const f16* Rb0 = RpT + (size_t)b*((size_t)NT*576*32) + (size_t)jh*(192*32);
  const float* facb = Fac + ((size_t)bg*HW + m0)*NBLK;
  int srow = tid >> 2, scs = (tid & 3) ^ ((srow >> 1) & 3);
  int r2 = (tid + 384) >> 2, c2 = ((tid + 384) & 3) ^ ((r2 >> 1) & 3);
  {
    f16* fl = (f16*)(smem + 28672);
    for (int i = tid; i < 32*NBLK; i += 384){
      int mm = i / NBLK, k = i - mm*NBLK;
      fl[mm*64 + k] = (f16)facb[(size_t)mm*NBLK + k];
    }
  }
  if (tid < 128) gl16(Sb + (size_t)srow*SW2 + scs*8, smem + tid*16);
  gl16(Rb0 + (size_t)srow*32 + scs*8, smem + 4096 + tid*16);
  gl16(Rb0 + (size_t)r2*32 + c2*8, smem + 4096 + (tid+384)*16);
  __syncthreads();
  int cur = 0;
  for (int t = 0; t < NT; ++t){
    char* Sc = smem + cur*2048;
    char* Rc = smem + 4096 + cur*12288;
    if (t + 1 < NT){
      char* Sn = smem + (cur^1)*2048;
      char* Rn = smem + 4096 + (cur^1)*12288;
      if (tid < 128) gl16(Sb + (size_t)srow*SW2 + (t+1)*32 + scs*8, Sn + tid*16);
      const f16* Rb = Rb0 + (size_t)(t+1)*(576*32);
      gl16(Rb + (size_t)srow*32 + scs*8, Rn + tid*16);
      gl16(Rb + (size_t)r2*32 + c2*8, Rn + (tid+384)*16);
    }
    int nb = t >> 2;
    f16 fac = ((f16*)(smem + 28672))[lr*64 + nb];
    f16x8 sv = *reinterpret_cast<const f16x8*>(Sc + abyte);
    f16x8 pa = sv * fac;
    #pragma unroll
    for (int nt = 0; nt < 4; nt++){
      f16x8 bv = *reinterpret_cast<const f16x8*>(Rc + rbyte[nt]);
      acc[nt] = __builtin_amdgcn_mfma_f32_16x16x32_f16(pa, bv, acc[nt], 0, 0, 0);
    }
    __syncthreads();
    cur ^= 1;
  }
  // epilogue: stage [192 j][32 m] in LDS (pad to 40 h16/row), coalesced store
  __syncthreads();
  {
    h16* Tl = (h16*)smem;
    #pragma unroll
    for (int nt = 0; nt < 4; nt++)
      #pragma unroll
      for (int i = 0; i < 4; i++)
        Tl[(wc*64 + nt*16 + cl)*40 + wm*16 + ch*4 + i] = __float2half(acc[nt][i]);
    __syncthreads();
    // 192 rows x 64 valid bytes = 768 uint4; 384 threads x 2 reps
    int idx = tid;
    #pragma unroll
    for (int rep = 0; rep < 2; rep++, idx += 384){
      int j0 = idx >> 2, q = idx & 3;
      uint4 v = *reinterpret_cast<const uint4*>((const char*)Tl + j0*80 + q*16);
      h16* dst = T + ((size_t)b*576 + jh*192 + j0)*HW + m0 + q*8;
      *reinterpret_cast<uint4*>(dst) = v;
    }
  }
}

// out[b,co,y,x] = x + 0.25 * fold(T[j][m]); coalesced T reads.
__global__ __launch_bounds__(256) void k_fold(const h16* __restrict__ T, const float* __restrict__ x,
    void* __restrict__ out, const int* __restrict__ flag){
  int id = blockIdx.x * 256 + threadIdx.x;
  if (id >= NB * 64 * HW) return;
  int b = id / (64*HW), id2 = id - b*(64*HW);
  int co = id2 / HW, p = id2 - co * HW;
  int y = p / 48, xx = p - y * 48;
  float acc = 0.f;
  #pragma unroll
  for (int dy = -1; dy <= 1; dy++){
    int yy = y + dy; if (yy < 0 || yy >= 48) continue;
    #pragma unroll
    for (int dx = -1; dx <= 1; dx++){
      int x2 = xx + dx; if (x2 < 0 || x2 >= 48) continue;
      int j = co*9 + (1-dy)*3 + (1-dx);
      acc += __half2float(T[((size_t)b*576 + j)*HW + yy*48 + x2]);
    }
  }
  size_t gi = (size_t)id;
  float r = x[gi] + 0.25f * acc;
  if (flag[0]) ((__hip_bfloat16*)out)[gi] = __float2bfloat16(r);
  else         ((float*)out)[gi] = r;
}

extern "C" void kernel_launch(void* const* d_in, const int* in_sizes, int n_in,
                              void* d_out, int out_size, void* d_ws, size_t ws_size,
                              hipStream_t stream){
  (void)out_size; (void)n_in;

  char* cur = (char*)d_ws;
  auto carve = [&](size_t bytes)->char*{
    char* p = cur; cur += (bytes + 255) & ~(size_t)255; return p;
  };
  int*   flag  = (int*)  carve(4);
  float* canon[10];
  for (int i = 0; i < 10; i++) canon[i] = (float*)carve((size_t)in_sizes[i] * 4);
  float* xc = canon[0];
  float* Wb = canon[1]; float* bb = canon[2]; float* ab = canon[3];
  float* Wm = canon[4]; float* bm = canon[5]; float* am = canon[6];
  float* Wa = canon[7]; float* ba = canon[8]; float* aa = canon[9];

  h16*   xs    = (h16*)  carve((size_t)NB * 64 * NP * 2);
  float* mbuf  = (float*)carve((size_t)NB * 32 * HW * 4);
  float* mat   = (float*)carve((size_t)NB * 32 * NP * 4);
  float* qbuf  = (float*)carve((size_t)NB * NP * 4);
  float* ninv  = (float*)carve((size_t)NB * NP * 4);
  h16*   baseh = (h16*)  carve((size_t)NB * 64 * NP * 2);
  h16*   U     = (h16*)  carve((size_t)NB * HW * 288 * 2);
  h16*   RpT   = (h16*)  carve((size_t)NB * NT * 576 * 32 * 2);
  h16*   T     = (h16*)  carve((size_t)NB * 576 * HW * 2);

  size_t fixed = (size_t)(cur - (char*)d_ws);
  size_t perb  = (((size_t)NPAD*288*2 + 255) & ~(size_t)255)
               + (((size_t)HW*SW2*2 + 255) & ~(size_t)255)
               + 3 * (((size_t)HW*NBLK*4 + 255) & ~(size_t)255);
  size_t avail = (ws_size > fixed) ? ws_size - fixed : 0;
  int g = (int)(avail / perb);
  if (g < 1) g = 1;
  if (g > NB) g = NB;
  h16*   Wp  = (h16*)  carve((size_t)g * NPAD * 288 * 2);
  h16*   S16 = (h16*)  carve((size_t)g * HW * SW2 * 2);
  float* Pm  = (float*)carve((size_t)g * HW * NBLK * 4);
  float* Ps  = (float*)carve((size_t)g * HW * NBLK * 4);
  float* Fac = (float*)carve((size_t)g * HW * NBLK * 4);

  k_detect<<<1, 256, 0, stream>>>(d_in[0], flag);
  {
    CanonArgs ca; int tot = 0;
    for (int i = 0; i < 10; i++){
      ca.src[i] = d_in[i]; ca.dst[i] = canon[i];
      tot += in_sizes[i]; ca.end[i] = tot;
    }
    k_canon_all<<<(tot + 255)/256, 256, 0, stream>>>(ca, tot, flag);
  }

  k_resize<<<((size_t)NB*NCH*NP + 255)/256, 256, 0, stream>>>(xc, xs);

  dim3 gm((NP + 63)/64, NB);
  k_conv1x1<false><<<gm, 256, 0, stream>>>(xs, Wm, bm, am, (void*)mat,   NP, 32, (size_t)64*NP, (size_t)32*NP, NP, NP);
  k_conv1x1<true ><<<gm, 256, 0, stream>>>(xs, Wa, ba, aa, (void*)baseh, NP, 64, (size_t)64*NP, (size_t)64*NP, NP, NP);
  dim3 gb2((HW + 63)/64, NB);
  k_conv1x1<false><<<gb2, 256, 0, stream>>>(xs, Wb, bb, ab, (void*)mbuf, HW, 32, (size_t)64*NP, (size_t)32*HW, NP, HW);

  k_sq  <<<(NB*NP + 255)/256, 256, 0, stream>>>(mat, qbuf);
  k_ninv<<<(NB*NP + 255)/256, 256, 0, stream>>>(qbuf, ninv);
  k_packU<<<((size_t)NB*HW*288 + 255)/256, 256, 0, stream>>>(mbuf, U);
  k_packR<<<((size_t)NB*NT*576*32 + 255)/256, 256, 0, stream>>>(baseh, RpT);

  for (int b0 = 0; b0 < NB; b0 += g){
    int gc = (b0 + g <= NB) ? g : (NB - b0);
    k_packW<<<((size_t)gc*NPAD*288 + 255)/256, 256, 0, stream>>>(mat, ninv, Wp, b0, gc);
    dim3 g1(NBLK, HW/128, gc);
    k_gemm1m<<<g1, 512, 0, stream>>>((const f16*)U, (const f16*)Wp, S16, Pm, Ps, b0);
    k_sfac<<<(gc*HW + 3)/4, 256, 0, stream>>>(Pm, Ps, Fac, gc);
    int nwg2 = 3 * 72 * gc;
    k_gemm2n<<<nwg2, 384, 0, stream>>>((const f16*)S16, (const f16*)RpT, Fac, T, b0);
  }

  k_fold<<<(NB*64*HW + 255)/256, 256, 0, stream>>>(T, xc, d_out, flag);
}

// Round 10
// 366.066 us; speedup vs baseline: 9.8609x; 1.2801x over previous
//
#include <hip/hip_runtime.h>
#include <hip/hip_bf16.h>
#include <hip/hip_fp16.h>

typedef __half h16;
typedef _Float16 f16;
typedef f16 f16x8 __attribute__((ext_vector_type(8)));
typedef __attribute__((ext_vector_type(4))) float f32x4;

#define NB 4
#define NCH 64
#define HW 2304      // 48*48
#define NP 7470      // total patches across 5 scales
#define NPAD 7552    // 59*128 = 236*32
#define NT 236       // k-tiles of 32
#define NBLK 59      // 128-col blocks
#define SW2 NPAD

__device__ __forceinline__ float us2f(unsigned short u){
  unsigned v = (unsigned)u << 16; float f; __builtin_memcpy(&f, &v, 4); return f;
}
__device__ __forceinline__ void gl16(const void* g, void* l){
  __builtin_amdgcn_global_load_lds((const __attribute__((address_space(1))) unsigned int*)g,
                                   (__attribute__((address_space(3))) unsigned int*)l, 16, 0, 0);
}

// n -> (scale offset, dim, y, x). dims 48,43,38,33,28; offsets 0,2304,4153,5597,6686
__device__ __forceinline__ void n_decode(int n, int& off, int& d, int& y, int& x){
  if (n < 2304)      { off = 0;    d = 48; }
  else if (n < 4153) { off = 2304; d = 43; }
  else if (n < 5597) { off = 4153; d = 38; }
  else if (n < 6686) { off = 5597; d = 33; }
  else               { off = 6686; d = 28; }
  int l = n - off; y = l / d; x = l - y * d;
}

// ---- dtype probe (proven R3-R9) ----
__global__ __launch_bounds__(256) void k_detect(const void* __restrict__ x, int* __restrict__ flag){
  const unsigned short* u = (const unsigned short*)x;
  int tid = threadIdx.x;
  int c = 0;
  for (int i = tid; i < 8192; i += 256){
    float v = us2f(u[i]);
    float a = fabsf(v);
    if (v == 0.f || (a > 1e-5f && a < 1e3f)) c++;
  }
  #pragma unroll
  for (int o = 1; o < 64; o <<= 1) c += __shfl_xor(c, o);
  __shared__ int wr[4];
  if ((tid & 63) == 0) wr[tid >> 6] = c;
  __syncthreads();
  if (tid == 0) flag[0] = ((wr[0]+wr[1]+wr[2]+wr[3]) > 7000) ? 1 : 0;
}

struct CanonArgs { const void* src[10]; float* dst[10]; int end[10]; };

__global__ __launch_bounds__(256) void k_canon_all(CanonArgs a, int tot, const int* __restrict__ flag){
  int id = blockIdx.x * 256 + threadIdx.x;
  if (id >= tot) return;
  int k = 0;
  while (id >= a.end[k]) k++;
  int local = id - (k ? a.end[k-1] : 0);
  float v;
  if (flag[0]) v = us2f(((const unsigned short*)a.src[k])[local]);
  else         v = ((const float*)a.src[k])[local];
  a.dst[k][local] = v;
}

// Bilinear resize: thread per output element (b,c,n); coalesced writes.
__global__ __launch_bounds__(256) void k_resize(const float* __restrict__ x, h16* __restrict__ xs){
  int id = blockIdx.x * 256 + threadIdx.x;
  if (id >= NB * NCH * NP) return;
  int b = id / (NCH*NP), rem = id - b*(NCH*NP);
  int c = rem / NP, n = rem - c*NP;
  int off, d, y, xx; n_decode(n, off, d, y, xx);
  const float* pc = x + ((size_t)b * NCH + c) * HW;
  float v;
  if (off == 0){
    v = pc[y*48 + xx];
  } else {
    float cy = (y + 0.5f) * (48.0f / (float)d) - 0.5f;
    float cx = (xx + 0.5f) * (48.0f / (float)d) - 0.5f;
    int y0 = (int)floorf(cy), x0 = (int)floorf(cx);
    float fy = cy - (float)y0, fx = cx - (float)x0;
    int y1 = min(y0 + 1, 47), x1 = min(x0 + 1, 47);
    y0 = max(y0, 0); x0 = max(x0, 0);
    v = (1.f-fy)*((1.f-fx)*pc[y0*48+x0] + fx*pc[y0*48+x1])
      + fy*((1.f-fx)*pc[y1*48+x0] + fx*pc[y1*48+x1]);
  }
  xs[id] = __float2half(v);
}

// 1x1 conv (Cin=64) + PReLU; in f16 [64][rs_in]; out fp32 or f16.
template<bool OB>
__global__ __launch_bounds__(256) void k_conv1x1(const h16* __restrict__ in, const float* __restrict__ Wt,
    const float* __restrict__ bias, const float* __restrict__ alpha, void* __restrict__ outv,
    int npix, int cout, size_t in_bstride, size_t out_bstride, int rs_in, int rs_out){
  __shared__ float Wl[64*64];
  __shared__ float it[64][64];
  int b = blockIdx.y;
  int n0 = blockIdx.x * 64;
  int tid = threadIdx.x;
  const h16* ib = in + (size_t)b * in_bstride;
  for (int i = tid; i < cout * 64; i += 256) Wl[i] = Wt[i];
  for (int i = tid; i < 64 * 64; i += 256){
    int ci = i >> 6, nn = i & 63;
    int n = n0 + nn;
    it[ci][nn] = (n < npix) ? __half2float(ib[(size_t)ci * rs_in + n]) : 0.f;
  }
  __syncthreads();
  float al = alpha[0];
  for (int oi = tid; oi < cout * 64; oi += 256){
    int co = oi >> 6, nn = oi & 63;
    float acc = bias[co];
    #pragma unroll
    for (int ci = 0; ci < 64; ci++) acc = fmaf(Wl[co*64+ci], it[ci][nn], acc);
    acc = acc >= 0.f ? acc : al * acc;
    int n = n0 + nn;
    if (n < npix){
      size_t idx = (size_t)b * out_bstride + (size_t)co * rs_out + n;
      if constexpr (OB) ((h16*)outv)[idx] = __float2half(acc);
      else              ((float*)outv)[idx] = acc;
    }
  }
}

// pass 1: q[b][n] = sum_c mat[c][n]^2 (coalesced over n)
__global__ __launch_bounds__(256) void k_sq(const float* __restrict__ mat, float* __restrict__ q){
  int id = blockIdx.x * 256 + threadIdx.x;
  if (id >= NB * NP) return;
  int b = id / NP, n = id - b * NP;
  const float* mp = mat + (size_t)b * 32 * NP + n;
  float s = 0.f;
  #pragma unroll
  for (int c = 0; c < 32; c++){ float v = mp[(size_t)c * NP]; s += v * v; }
  q[id] = s;
}

// pass 2: ninv[b][n] = 1/max(sqrt(9-tap sum of q), 1e-4)
__global__ __launch_bounds__(256) void k_ninv(const float* __restrict__ q, float* __restrict__ ninv){
  int id = blockIdx.x * 256 + threadIdx.x;
  if (id >= NB * NP) return;
  int b = id / NP, n = id - b * NP;
  int off, d, y, x; n_decode(n, off, d, y, x);
  const float* qb = q + (size_t)b * NP + off;
  float s = 0.f;
  #pragma unroll
  for (int dy = -1; dy <= 1; dy++){
    int yy = y + dy; if (yy < 0 || yy >= d) continue;
    #pragma unroll
    for (int dx = -1; dx <= 1; dx++){
      int xx = x + dx; if (xx < 0 || xx >= d) continue;
      s += qb[yy * d + xx];
    }
  }
  ninv[id] = 1.f / fmaxf(sqrtf(s), 1e-4f);
}

// unfold match_base -> U[b][2304][288] f16
__global__ __launch_bounds__(256) void k_packU(const float* __restrict__ mb, h16* __restrict__ U){
  int id = blockIdx.x * 256 + threadIdx.x;
  if (id >= NB * HW * 288) return;
  int b = id / (HW*288), rem = id - b*(HW*288);
  int p = rem / 288, k = rem - p * 288;
  int c = k / 9, r = k - c * 9, kh = r / 3, kw = r - kh * 3;
  int y = p / 48 + kh - 1, x = (p % 48) + kw - 1;
  float v = 0.f;
  if (y >= 0 && y < 48 && x >= 0 && x < 48)
    v = mb[((size_t)b * 32 + c) * HW + y * 48 + x];
  U[id] = __float2half(v);
}

// unfold mat * (10*ninv) -> Wp[g][NPAD][288] f16
__global__ __launch_bounds__(256) void k_packW(const float* __restrict__ mat, const float* __restrict__ ninv,
                                               h16* __restrict__ Wp, int b0, int g){
  int id = blockIdx.x * 256 + threadIdx.x;
  if (id >= g * NPAD * 288) return;
  int bg = id / (NPAD*288), rem = id - bg*(NPAD*288);
  int n = rem / 288, k = rem - n * 288;
  float v = 0.f;
  if (n < NP){
    int b = b0 + bg;
    int c = k / 9, r = k - c * 9, kh = r / 3, kw = r - kh * 3;
    int off, d, y, x; n_decode(n, off, d, y, x);
    int yy = y + kh - 1, xx = x + kw - 1;
    if (yy >= 0 && yy < d && xx >= 0 && xx < d)
      v = mat[((size_t)b * 32 + c) * NP + off + yy * d + xx] * 10.f * ninv[(size_t)b*NP + n];
  }
  Wp[id] = __float2half(v);
}

// unfold base (f16) -> RpT[b][t][576][32] f16
__global__ __launch_bounds__(256) void k_packR(const h16* __restrict__ src, h16* __restrict__ dst){
  int id = blockIdx.x * 256 + threadIdx.x;
  if (id >= NB * NT * 576 * 32) return;
  int b = id / (NT*576*32), rem = id - b*(NT*576*32);
  int t = rem / (576*32), rem2 = rem - t*(576*32);
  int j = rem2 / 32, kl = rem2 - j*32;
  int n = t*32 + kl;
  h16 v = __float2half(0.f);
  if (n < NP){
    int c = j / 9, r = j - c * 9, kh = r / 3, kw = r - kh * 3;
    int off, d, y, x; n_decode(n, off, d, y, x);
    int yy = y + kh - 1, xx = x + kw - 1;
    if (yy >= 0 && yy < d && xx >= 0 && xx < d)
      v = src[((size_t)b * 64 + c) * NP + off + yy * d + xx];
  }
  dst[id] = v;
}

// GEMM1 + fused block-local softmax stats; dbuf prefetch, 2-way swizzle.
// S16[bg][m][n]=exp(s-Mloc) f16 (pad->0); Pm/Ps layout [bg][m][NBLK].
__global__ __launch_bounds__(512) void k_gemm1m(const f16* __restrict__ U, const f16* __restrict__ Wp,
    h16* __restrict__ S16, float* __restrict__ Pm, float* __restrict__ Ps, int b0){
  int bg = blockIdx.z, b = b0 + bg;
  int m0 = blockIdx.y * 128, n0 = blockIdx.x * 128;
  int tid = threadIdx.x, l = tid & 63, w = tid >> 6;
  int wm = w >> 1, wn = w & 1;
  int ch = l >> 4, cl = l & 15;
  __shared__ __align__(16) char At[2][8192];
  __shared__ __align__(16) char Bt[2][8192];
  __shared__ float mred[128][2];
  __shared__ float sred[128][2];
  f32x4 acc[2][4] = {};
  const f16* Ub = U + ((size_t)b * HW + m0) * 288;
  const f16* Wb = Wp + ((size_t)bg * NPAD + n0) * 288;
  int abyte[2], bbyte[4];
  #pragma unroll
  for (int mt = 0; mt < 2; mt++){
    int lr = wm*32 + mt*16 + cl;
    abyte[mt] = lr*64 + ((ch ^ ((lr>>1)&3))<<4);
  }
  #pragma unroll
  for (int nt = 0; nt < 4; nt++){
    int lr = wn*64 + nt*16 + cl;
    bbyte[nt] = lr*64 + ((ch ^ ((lr>>1)&3))<<4);
  }
  int srow = tid >> 2, scs = (tid & 3) ^ ((srow >> 1) & 3);
  gl16(Ub + (size_t)srow*288 + 0 + scs*8, At[0] + tid*16);
  gl16(Wb + (size_t)srow*288 + 0 + scs*8, Bt[0] + tid*16);
  __syncthreads();
  int cur = 0;
  for (int k0 = 0; k0 < 288; k0 += 32){
    if (k0 + 32 < 288){
      gl16(Ub + (size_t)srow*288 + k0 + 32 + scs*8, At[cur^1] + tid*16);
      gl16(Wb + (size_t)srow*288 + k0 + 32 + scs*8, Bt[cur^1] + tid*16);
    }
    f16x8 a[2], bv[4];
    #pragma unroll
    for (int mt = 0; mt < 2; mt++) a[mt] = *reinterpret_cast<const f16x8*>(At[cur] + abyte[mt]);
    #pragma unroll
    for (int nt = 0; nt < 4; nt++) bv[nt] = *reinterpret_cast<const f16x8*>(Bt[cur] + bbyte[nt]);
    #pragma unroll
    for (int mt = 0; mt < 2; mt++)
      #pragma unroll
      for (int nt = 0; nt < 4; nt++)
        acc[mt][nt] = __builtin_amdgcn_mfma_f32_16x16x32_f16(a[mt], bv[nt], acc[mt][nt], 0, 0, 0);
    __syncthreads();
    cur ^= 1;
  }
  #pragma unroll
  for (int mt = 0; mt < 2; mt++)
    #pragma unroll
    for (int i = 0; i < 4; i++){
      float v = -3e38f;
      #pragma unroll
      for (int nt = 0; nt < 4; nt++){
        int gn = n0 + wn*64 + nt*16 + cl;
        float t = acc[mt][nt][i];
        v = fmaxf(v, (gn < NP) ? t : -3e38f);
      }
      v = fmaxf(v, __shfl_xor(v, 1));
      v = fmaxf(v, __shfl_xor(v, 2));
      v = fmaxf(v, __shfl_xor(v, 4));
      v = fmaxf(v, __shfl_xor(v, 8));
      if (cl == 0) mred[wm*32 + mt*16 + ch*4 + i][wn] = v;
    }
  __syncthreads();
  #pragma unroll
  for (int mt = 0; mt < 2; mt++)
    #pragma unroll
    for (int i = 0; i < 4; i++){
      int r = wm*32 + mt*16 + ch*4 + i;
      float Ml = fmaxf(mred[r][0], mred[r][1]);
      int gm = m0 + r;
      float s = 0.f;
      #pragma unroll
      for (int nt = 0; nt < 4; nt++){
        int gn = n0 + wn*64 + nt*16 + cl;
        float e = (gn < NP) ? __expf(acc[mt][nt][i] - Ml) : 0.f;
        S16[((size_t)bg*HW + gm)*SW2 + gn] = __float2half(e);
        s += e;
      }
      s += __shfl_xor(s, 1);
      s += __shfl_xor(s, 2);
      s += __shfl_xor(s, 4);
      s += __shfl_xor(s, 8);
      if (cl == 0) sred[r][wn] = s;
    }
  __syncthreads();
  if (tid < 128){
    float Mf = fmaxf(mred[tid][0], mred[tid][1]);
    float L  = sred[tid][0] + sred[tid][1];
    size_t o = ((size_t)bg*HW + m0 + tid)*NBLK + blockIdx.x;
    Pm[o] = Mf; Ps[o] = L;
  }
}

// combine partials (wave per row): Fac[bg][m][k] = exp(Mloc-Mglob)/L_glob
__global__ __launch_bounds__(256) void k_sfac(const float* __restrict__ Pm, const float* __restrict__ Ps,
                                              float* __restrict__ Fac, int gc){
  int rid = blockIdx.x * 4 + (threadIdx.x >> 6);
  int lane = threadIdx.x & 63;
  if (rid >= gc * HW) return;
  const float* pm = Pm + (size_t)rid * NBLK;
  const float* ps = Ps + (size_t)rid * NBLK;
  float mv = (lane < NBLK) ? pm[lane] : -3e38f;
  float sv = (lane < NBLK) ? ps[lane] : 0.f;
  float M = mv;
  #pragma unroll
  for (int o = 1; o < 64; o <<= 1) M = fmaxf(M, __shfl_xor(M, o));
  float e = (lane < NBLK) ? __expf(mv - M) : 0.f;
  float c = e * sv;
  #pragma unroll
  for (int o = 1; o < 64; o <<= 1) c += __shfl_xor(c, o);
  float inv = 1.f / c;
  if (lane < NBLK) Fac[(size_t)rid * NBLK + lane] = e * inv;
}

// GEMM2: T[b][j][m] = sum_k (S16[m][k]*Fac) * RpT[k][j]
// BM=64, BN=192; 512 thr (8 waves = 2 wm x 4 wc); 3-deep LDS pipeline with
// counted vmcnt(4) + raw barriers (T3/T4); conflict-free fl; j-major epilogue.
__global__ __launch_bounds__(512) void k_gemm2n(const f16* __restrict__ S16, const f16* __restrict__ RpT,
    const float* __restrict__ Fac, h16* __restrict__ T, int b0){
  int nwg = gridDim.x;
  int p = blockIdx.x;
  int L = (nwg % 8 == 0) ? ((p & 7)*(nwg>>3) + (p>>3)) : p;
  int jh = L % 3; int t1 = L / 3; int my = t1 % 36; int bg = t1 / 36;
  int b = b0 + bg;
  int m0 = my * 64;
  int tid = threadIdx.x, l = tid & 63, w = tid >> 6;
  int wm = w >> 2, wc = w & 3;
  int ch = l >> 4, cl = l & 15;
  __shared__ __align__(16) char smem[56704];
  // S bufs @ 0/4096/8192 (4KB each); R bufs @ 12288/24576/36864 (12KB each);
  // fl @ 49152: f16 [NBLK][64] (7552 B, stride-2 consecutive in m -> conflict-free)
  f32x4 acc[2][3] = {};
  int lrm[2], abyte[2], rbyte[3];
  #pragma unroll
  for (int mt = 0; mt < 2; mt++){
    lrm[mt] = wm*32 + mt*16 + cl;
    abyte[mt] = lrm[mt]*64 + ((ch ^ ((lrm[mt]>>1)&3))<<4);
  }
  #pragma unroll
  for (int nt = 0; nt < 3; nt++){
    int jr = wc*48 + nt*16 + cl;
    rbyte[nt] = jr*64 + ((ch ^ ((jr>>1)&3))<<4);
  }
  const f16* Sb  = S16 + ((size_t)bg*HW + m0)*SW2;
  const f16* Rb0 = RpT + (size_t)b*((size_t)NT*576*32) + (size_t)jh*(192*32);
  const float* facb = Fac + ((size_t)bg*HW + m0)*NBLK;

  // stage one tile into buffer bi; exactly 2 gl16 per thread
  auto STAGE = [&](int t, int bi){
    char* dS = smem + bi*4096;
    char* dR = smem + 12288 + bi*12288;
    const f16* Rb = Rb0 + (size_t)t*(576*32);
    if (tid < 256){
      int row = tid >> 2, cs = (tid & 3) ^ ((row >> 1) & 3);
      gl16(Sb + (size_t)row*SW2 + t*32 + cs*8, dS + tid*16);
      int i2 = tid + 512;
      int r2 = i2 >> 2, c2 = (i2 & 3) ^ ((r2 >> 1) & 3);
      gl16(Rb + (size_t)r2*32 + c2*8, dR + i2*16);
    } else {
      int i1 = tid - 256;
      int r1 = i1 >> 2, c1 = (i1 & 3) ^ ((r1 >> 1) & 3);
      gl16(Rb + (size_t)r1*32 + c1*8, dR + i1*16);
      int r2 = tid >> 2, c2 = (tid & 3) ^ ((r2 >> 1) & 3);
      gl16(Rb + (size_t)r2*32 + c2*8, dR + tid*16);
    }
  };

  { // fl preload: fl[nb*64+m] = Fac[m][nb]
    f16* fl = (f16*)(smem + 49152);
    for (int i = tid; i < NBLK*64; i += 512){
      int nb = i >> 6, mm = i & 63;
      fl[i] = (f16)facb[(size_t)mm*NBLK + nb];
    }
  }
  STAGE(0, 0);
  STAGE(1, 1);
  __syncthreads();   // drains vmcnt to 0; fl visible

  int cur = 0;
  for (int t = 0; t < NT; ++t){
    int nx = cur + 2; if (nx >= 3) nx -= 3;
    if (t + 2 < NT){
      STAGE(t + 2, nx);
      asm volatile("s_waitcnt vmcnt(4)" ::: "memory");   // tile t landed; t+1,t+2 in flight
    } else if (t + 1 < NT){
      asm volatile("s_waitcnt vmcnt(2)" ::: "memory");
    } else {
      asm volatile("s_waitcnt vmcnt(0)" ::: "memory");
    }
    __builtin_amdgcn_s_barrier();
    asm volatile("" ::: "memory");    // keep LDS reads below the barrier
    const char* Sc = smem + cur*4096;
    const char* Rc = smem + 12288 + cur*12288;
    const f16* fl = (const f16*)(smem + 49152);
    int nb = t >> 2;
    f16x8 pa[2];
    #pragma unroll
    for (int mt = 0; mt < 2; mt++){
      f16 fac = fl[nb*64 + lrm[mt]];
      f16x8 sv = *reinterpret_cast<const f16x8*>(Sc + abyte[mt]);
      pa[mt] = sv * fac;
    }
    #pragma unroll
    for (int nt = 0; nt < 3; nt++){
      f16x8 bv = *reinterpret_cast<const f16x8*>(Rc + rbyte[nt]);
      #pragma unroll
      for (int mt = 0; mt < 2; mt++)
        acc[mt][nt] = __builtin_amdgcn_mfma_f32_16x16x32_f16(pa[mt], bv, acc[mt][nt], 0, 0, 0);
    }
    asm volatile("s_waitcnt lgkmcnt(0)" ::: "memory");   // LDS reads done before rotate
    __builtin_amdgcn_s_barrier();
    cur = cur + 1; if (cur >= 3) cur = 0;
  }

  // epilogue: stage [192 j][64 m] in LDS (row pad 72 h16 = 144B), j-major store
  {
    h16* Tl = (h16*)smem;
    #pragma unroll
    for (int nt = 0; nt < 3; nt++)
      #pragma unroll
      for (int mt = 0; mt < 2; mt++)
        #pragma unroll
        for (int i = 0; i < 4; i++)
          Tl[(wc*48 + nt*16 + cl)*72 + wm*32 + mt*16 + ch*4 + i] = __float2half(acc[mt][nt][i]);
    __syncthreads();
    // 192 rows x 128 valid bytes = 1536 uint4; 512 thr x 3 reps
    #pragma unroll
    for (int rep = 0; rep < 3; rep++){
      int idx = tid + rep*512;
      int j0 = idx >> 3, q = idx & 7;
      uint4 v = *reinterpret_cast<const uint4*>((const char*)Tl + j0*144 + q*16);
      h16* dst = T + ((size_t)b*576 + jh*192 + j0)*HW + m0 + q*8;
      *reinterpret_cast<uint4*>(dst) = v;
    }
  }
}

// out[b,co,y,x] = x + 0.25 * fold(T[j][m]); coalesced T reads.
__global__ __launch_bounds__(256) void k_fold(const h16* __restrict__ T, const float* __restrict__ x,
    void* __restrict__ out, const int* __restrict__ flag){
  int id = blockIdx.x * 256 + threadIdx.x;
  if (id >= NB * 64 * HW) return;
  int b = id / (64*HW), id2 = id - b*(64*HW);
  int co = id2 / HW, p = id2 - co * HW;
  int y = p / 48, xx = p - y * 48;
  float acc = 0.f;
  #pragma unroll
  for (int dy = -1; dy <= 1; dy++){
    int yy = y + dy; if (yy < 0 || yy >= 48) continue;
    #pragma unroll
    for (int dx = -1; dx <= 1; dx++){
      int x2 = xx + dx; if (x2 < 0 || x2 >= 48) continue;
      int j = co*9 + (1-dy)*3 + (1-dx);
      acc += __half2float(T[((size_t)b*576 + j)*HW + yy*48 + x2]);
    }
  }
  size_t gi = (size_t)id;
  float r = x[gi] + 0.25f * acc;
  if (flag[0]) ((__hip_bfloat16*)out)[gi] = __float2bfloat16(r);
  else         ((float*)out)[gi] = r;
}

extern "C" void kernel_launch(void* const* d_in, const int* in_sizes, int n_in,
                              void* d_out, int out_size, void* d_ws, size_t ws_size,
                              hipStream_t stream){
  (void)out_size; (void)n_in;

  char* cur = (char*)d_ws;
  auto carve = [&](size_t bytes)->char*{
    char* p = cur; cur += (bytes + 255) & ~(size_t)255; return p;
  };
  int*   flag  = (int*)  carve(4);
  float* canon[10];
  for (int i = 0; i < 10; i++) canon[i] = (float*)carve((size_t)in_sizes[i] * 4);
  float* xc = canon[0];
  float* Wb = canon[1]; float* bb = canon[2]; float* ab = canon[3];
  float* Wm = canon[4]; float* bm = canon[5]; float* am = canon[6];
  float* Wa = canon[7]; float* ba = canon[8]; float* aa = canon[9];

  h16*   xs    = (h16*)  carve((size_t)NB * 64 * NP * 2);
  float* mbuf  = (float*)carve((size_t)NB * 32 * HW * 4);
  float* mat   = (float*)carve((size_t)NB * 32 * NP * 4);
  float* qbuf  = (float*)carve((size_t)NB * NP * 4);
  float* ninv  = (float*)carve((size_t)NB * NP * 4);
  h16*   baseh = (h16*)  carve((size_t)NB * 64 * NP * 2);
  h16*   U     = (h16*)  carve((size_t)NB * HW * 288 * 2);
  h16*   RpT   = (h16*)  carve((size_t)NB * NT * 576 * 32 * 2);
  h16*   T     = (h16*)  carve((size_t)NB * 576 * HW * 2);

  size_t fixed = (size_t)(cur - (char*)d_ws);
  size_t perb  = (((size_t)NPAD*288*2 + 255) & ~(size_t)255)
               + (((size_t)HW*SW2*2 + 255) & ~(size_t)255)
               + 3 * (((size_t)HW*NBLK*4 + 255) & ~(size_t)255);
  size_t avail = (ws_size > fixed) ? ws_size - fixed : 0;
  int g = (int)(avail / perb);
  if (g < 1) g = 1;
  if (g > NB) g = NB;
  h16*   Wp  = (h16*)  carve((size_t)g * NPAD * 288 * 2);
  h16*   S16 = (h16*)  carve((size_t)g * HW * SW2 * 2);
  float* Pm  = (float*)carve((size_t)g * HW * NBLK * 4);
  float* Ps  = (float*)carve((size_t)g * HW * NBLK * 4);
  float* Fac = (float*)carve((size_t)g * HW * NBLK * 4);

  k_detect<<<1, 256, 0, stream>>>(d_in[0], flag);
  {
    CanonArgs ca; int tot = 0;
    for (int i = 0; i < 10; i++){
      ca.src[i] = d_in[i]; ca.dst[i] = canon[i];
      tot += in_sizes[i]; ca.end[i] = tot;
    }
    k_canon_all<<<(tot + 255)/256, 256, 0, stream>>>(ca, tot, flag);
  }

  k_resize<<<((size_t)NB*NCH*NP + 255)/256, 256, 0, stream>>>(xc, xs);

  dim3 gm((NP + 63)/64, NB);
  k_conv1x1<false><<<gm, 256, 0, stream>>>(xs, Wm, bm, am, (void*)mat,   NP, 32, (size_t)64*NP, (size_t)32*NP, NP, NP);
  k_conv1x1<true ><<<gm, 256, 0, stream>>>(xs, Wa, ba, aa, (void*)baseh, NP, 64, (size_t)64*NP, (size_t)64*NP, NP, NP);
  dim3 gb2((HW + 63)/64, NB);
  k_conv1x1<false><<<gb2, 256, 0, stream>>>(xs, Wb, bb, ab, (void*)mbuf, HW, 32, (size_t)64*NP, (size_t)32*HW, NP, HW);

  k_sq  <<<(NB*NP + 255)/256, 256, 0, stream>>>(mat, qbuf);
  k_ninv<<<(NB*NP + 255)/256, 256, 0, stream>>>(qbuf, ninv);
  k_packU<<<((size_t)NB*HW*288 + 255)/256, 256, 0, stream>>>(mbuf, U);
  k_packR<<<((size_t)NB*NT*576*32 + 255)/256, 256, 0, stream>>>(baseh, RpT);

  for (int b0 = 0; b0 < NB; b0 += g){
    int gc = (b0 + g <= NB) ? g : (NB - b0);
    k_packW<<<((size_t)gc*NPAD*288 + 255)/256, 256, 0, stream>>>(mat, ninv, Wp, b0, gc);
    dim3 g1(NBLK, HW/128, gc);
    k_gemm1m<<<g1, 512, 0, stream>>>((const f16*)U, (const f16*)Wp, S16, Pm, Ps, b0);
    k_sfac<<<(gc*HW + 3)/4, 256, 0, stream>>>(Pm, Ps, Fac, gc);
    int nwg2 = 3 * 36 * gc;
    k_gemm2n<<<nwg2, 512, 0, stream>>>((const f16*)S16, (const f16*)RpT, Fac, T, b0);
  }

  k_fold<<<(NB*64*HW + 255)/256, 256, 0, stream>>>(T, xc, d_out, flag);
}